// Round 1
// baseline (1024.688 us; speedup 1.0000x reference)
//
#include <hip/hip_runtime.h>
#include <hip/hip_bf16.h>

#define DEV static __device__ __forceinline__

DEV float leakys(float v) { return v > 0.f ? v : 0.2f * v; }
DEV float4 add4(float4 a, float4 b) { return make_float4(a.x+b.x, a.y+b.y, a.z+b.z, a.w+b.w); }
DEV float4 sub4(float4 a, float4 b) { return make_float4(a.x-b.x, a.y-b.y, a.z-b.z, a.w-b.w); }
DEV float4 max4(float4 a, float4 b) { return make_float4(fmaxf(a.x,b.x), fmaxf(a.y,b.y), fmaxf(a.z,b.z), fmaxf(a.w,b.w)); }
DEV float4 leaky4(float4 v) { return make_float4(leakys(v.x), leakys(v.y), leakys(v.z), leakys(v.w)); }
DEV float4 exp4(float4 v) { return make_float4(__expf(v.x), __expf(v.y), __expf(v.z), __expf(v.w)); }

// ---------------------------------------------------------------------------
// GEMM: C[N][COLS] = A[N][128] @ W[128][COLS], f32 vector FMA, K split in two
// 64-wide phases so LDS stays at 48 KB (<= 64 KB static limit).
// ---------------------------------------------------------------------------
template <int COLS>
__launch_bounds__(256, 2)
__global__ void gemm_k128(const float* __restrict__ A, const float* __restrict__ W,
                          float* __restrict__ C, int N) {
    constexpr int TX = COLS / 4;     // threads across columns (4 cols each)
    constexpr int TY = 256 / TX;
    constexpr int ROWS = TY * 8;     // rows per block (8 rows per thread)
    __shared__ float Wl[64 * COLS];
    __shared__ float Xl[ROWS * 64];
    const int t = threadIdx.x;
    const int row0 = blockIdx.x * ROWS;
    const int tx = t % TX, ty = t / TX;

    float4 acc[8];
#pragma unroll
    for (int r = 0; r < 8; r++) acc[r] = make_float4(0.f, 0.f, 0.f, 0.f);

    for (int kp = 0; kp < 128; kp += 64) {
        __syncthreads();
        // stage W rows [kp, kp+64)
        for (int i = t; i < 64 * COLS / 4; i += 256)
            ((float4*)Wl)[i] = ((const float4*)W)[(size_t)kp * (COLS / 4) + i];
        // stage X cols [kp, kp+64) for rows [row0, row0+ROWS)
        for (int i = t; i < ROWS * 16; i += 256) {
            int r = i >> 4, c = i & 15;
            int gr = row0 + r;
            float4 v = make_float4(0.f, 0.f, 0.f, 0.f);
            if (gr < N) v = ((const float4*)A)[(size_t)gr * 32 + (kp >> 2) + c];
            ((float4*)Xl)[r * 16 + c] = v;
        }
        __syncthreads();
#pragma unroll
        for (int k0 = 0; k0 < 64; k0 += 4) {
            float4 w0 = *(const float4*)&Wl[(k0 + 0) * COLS + tx * 4];
            float4 w1 = *(const float4*)&Wl[(k0 + 1) * COLS + tx * 4];
            float4 w2 = *(const float4*)&Wl[(k0 + 2) * COLS + tx * 4];
            float4 w3 = *(const float4*)&Wl[(k0 + 3) * COLS + tx * 4];
#pragma unroll
            for (int r = 0; r < 8; r++) {
                float4 xv = *(const float4*)&Xl[(ty * 8 + r) * 64 + k0];
                acc[r].x += xv.x * w0.x + xv.y * w1.x + xv.z * w2.x + xv.w * w3.x;
                acc[r].y += xv.x * w0.y + xv.y * w1.y + xv.z * w2.y + xv.w * w3.y;
                acc[r].z += xv.x * w0.z + xv.y * w1.z + xv.z * w2.z + xv.w * w3.z;
                acc[r].w += xv.x * w0.w + xv.y * w1.w + xv.z * w2.w + xv.w * w3.w;
            }
        }
    }
#pragma unroll
    for (int r = 0; r < 8; r++) {
        int gr = row0 + ty * 8 + r;
        if (gr < N) ((float4*)C)[(size_t)gr * (COLS / 4) + tx] = acc[r];
    }
}

// ---------------------------------------------------------------------------
// attention dot products: a_s[n,h] = sum_c h[n,h,c]*att_src[h,c] (layer 1)
// ---------------------------------------------------------------------------
__global__ void attdot1(const float* __restrict__ h, const float* __restrict__ asrc,
                        const float* __restrict__ adst, float* __restrict__ as,
                        float* __restrict__ ad, int N) {
    int t = threadIdx.x;
    int node = blockIdx.x * 2 + (t >> 7);
    int j = t & 127;
    if (node >= N) return;
    float v = h[(size_t)node * 128 + j];
    float s = v * asrc[j];
    float d = v * adst[j];
#pragma unroll
    for (int o = 1; o < 32; o <<= 1) { s += __shfl_xor(s, o); d += __shfl_xor(d, o); }
    if ((j & 31) == 0) { int head = j >> 5; as[node * 4 + head] = s; ad[node * 4 + head] = d; }
}

__global__ void attdot2(const float* __restrict__ h, const float* __restrict__ asrc,
                        const float* __restrict__ adst, float* __restrict__ as,
                        float* __restrict__ ad, int N) {
    int t = threadIdx.x;
    int node = blockIdx.x * 4 + (t >> 6);
    int j = t & 63;
    if (node >= N) return;
    float v = h[(size_t)node * 64 + j];
    float s = v * asrc[j];
    float d = v * adst[j];
#pragma unroll
    for (int o = 1; o < 64; o <<= 1) { s += __shfl_xor(s, o); d += __shfl_xor(d, o); }
    if (j == 0) { as[node] = s; ad[node] = d; }
}

// ---------------------------------------------------------------------------
// CSR build: histogram -> 2-level exclusive scan -> fill (src values, by dst)
// ---------------------------------------------------------------------------
__global__ void count_k(const int* __restrict__ dstIdx, int* __restrict__ counts, int E) {
    int e = blockIdx.x * 256 + threadIdx.x;
    if (e < E) atomicAdd(&counts[dstIdx[e]], 1);
}

__global__ void scan_block(const int* __restrict__ in, int* __restrict__ out,
                           int* __restrict__ bsums, int n) {
    __shared__ int lds[256];
    int t = threadIdx.x;
    int base = blockIdx.x * 1024 + t * 4;
    int v0 = 0, v1 = 0, v2 = 0, v3 = 0;
    if (base + 0 < n) v0 = in[base + 0];
    if (base + 1 < n) v1 = in[base + 1];
    if (base + 2 < n) v2 = in[base + 2];
    if (base + 3 < n) v3 = in[base + 3];
    int tsum = v0 + v1 + v2 + v3;
    lds[t] = tsum;
    __syncthreads();
    int val = tsum;
    for (int o = 1; o < 256; o <<= 1) {
        int other = (t >= o) ? lds[t - o] : 0;
        __syncthreads();
        val += other; lds[t] = val;
        __syncthreads();
    }
    if (t == 255) bsums[blockIdx.x] = val;
    int run = val - tsum;  // exclusive prefix of this thread
    if (base + 0 < n) out[base + 0] = run; run += v0;
    if (base + 1 < n) out[base + 1] = run; run += v1;
    if (base + 2 < n) out[base + 2] = run; run += v2;
    if (base + 3 < n) out[base + 3] = run;
}

__global__ void scan_sums(int* __restrict__ bsums, int nb) {
    __shared__ int lds[256];
    int t = threadIdx.x;
    int orig = (t < nb) ? bsums[t] : 0;
    lds[t] = orig;
    __syncthreads();
    int val = orig;
    for (int o = 1; o < 256; o <<= 1) {
        int other = (t >= o) ? lds[t - o] : 0;
        __syncthreads();
        val += other; lds[t] = val;
        __syncthreads();
    }
    if (t < nb) bsums[t] = val - orig;  // exclusive
}

__global__ void add_offsets(int* __restrict__ rowptr, const int* __restrict__ bsums,
                            int* __restrict__ cursor, int n, int total) {
    int i = blockIdx.x * 256 + threadIdx.x;
    if (i < n) {
        int v = rowptr[i] + bsums[i >> 10];
        rowptr[i] = v;
        cursor[i] = v;
    } else if (i == n) {
        rowptr[n] = total;
    }
}

__global__ void fill_k(const int* __restrict__ srcIdx, const int* __restrict__ dstIdx,
                       int* __restrict__ cursor, int* __restrict__ esrc, int E) {
    int e = blockIdx.x * 256 + threadIdx.x;
    if (e < E) {
        int pos = atomicAdd(&cursor[dstIdx[e]], 1);
        esrc[pos] = srcIdx[e];
    }
}

// ---------------------------------------------------------------------------
// Layer-1 aggregation: one wave per dst node. Softmax over in-edges + implicit
// self-loop; lanes own 2 of 128 channels; +bias, ReLU.
// ---------------------------------------------------------------------------
__launch_bounds__(256)
__global__ void aggregate1(const float* __restrict__ h1, const float* __restrict__ as1,
                           const float* __restrict__ ad1, const int* __restrict__ rowptr,
                           const int* __restrict__ esrc, const float* __restrict__ b1,
                           float* __restrict__ out1, int N) {
    int wid = threadIdx.x >> 6, lane = threadIdx.x & 63;
    int node = blockIdx.x * 4 + wid;
    if (node >= N) return;
    float4 asn = *(const float4*)&as1[node * 4];
    float4 adn = *(const float4*)&ad1[node * 4];
    float4 aself = leaky4(add4(asn, adn));
    int start = rowptr[node], end = rowptr[node + 1];

    // pass A: segment max (incl. self-loop)
    float4 m = aself;
    for (int e = start + lane; e < end; e += 64) {
        float4 a = *(const float4*)&as1[esrc[e] * 4];
        m = max4(m, leaky4(add4(a, adn)));
    }
#pragma unroll
    for (int o = 1; o < 64; o <<= 1) {
        m.x = fmaxf(m.x, __shfl_xor(m.x, o));
        m.y = fmaxf(m.y, __shfl_xor(m.y, o));
        m.z = fmaxf(m.z, __shfl_xor(m.z, o));
        m.w = fmaxf(m.w, __shfl_xor(m.w, o));
    }
    // pass B: denominator
    float4 ssum = make_float4(0.f, 0.f, 0.f, 0.f);
    if (lane == 0) ssum = exp4(sub4(aself, m));
    for (int e = start + lane; e < end; e += 64) {
        float4 a = leaky4(add4(*(const float4*)&as1[esrc[e] * 4], adn));
        ssum = add4(ssum, exp4(sub4(a, m)));
    }
#pragma unroll
    for (int o = 1; o < 64; o <<= 1) {
        ssum.x += __shfl_xor(ssum.x, o);
        ssum.y += __shfl_xor(ssum.y, o);
        ssum.z += __shfl_xor(ssum.z, o);
        ssum.w += __shfl_xor(ssum.w, o);
    }
    // per-lane head selection: j0 = lane (heads 0/1), j1 = lane+64 (heads 2/3)
    int hA = lane >> 5;
    float mA = hA ? m.y : m.x;
    float mB = hA ? m.w : m.z;
    float invA = 1.f / ((hA ? ssum.y : ssum.x) + 1e-16f);
    float invB = 1.f / ((hA ? ssum.w : ssum.z) + 1e-16f);
    float adA = hA ? adn.y : adn.x;
    float adB = hA ? adn.w : adn.z;
    float selfA = hA ? aself.y : aself.x;
    float selfB = hA ? aself.w : aself.z;
    int j0 = lane, j1 = lane + 64;
    const float* hp = h1 + (size_t)node * 128;
    float acc0 = __expf(selfA - mA) * invA * hp[j0];
    float acc1 = __expf(selfB - mB) * invB * hp[j1];
    // pass C: weighted gather-accumulate (all lanes walk all edges together)
    for (int e = start; e < end; e++) {
        int s = esrc[e];
        const float* hq = h1 + (size_t)s * 128;
        float aA = leakys(as1[s * 4 + hA] + adA);
        float aB = leakys(as1[s * 4 + 2 + hA] + adB);
        acc0 += __expf(aA - mA) * invA * hq[j0];
        acc1 += __expf(aB - mB) * invB * hq[j1];
    }
    float o0 = acc0 + b1[j0];
    float o1 = acc1 + b1[j1];
    out1[(size_t)node * 128 + j0] = fmaxf(o0, 0.f);
    out1[(size_t)node * 128 + j1] = fmaxf(o1, 0.f);
}

// ---------------------------------------------------------------------------
// Layer-2 aggregation: H=1, C=64. One wave per dst node, lane = channel. +bias.
// ---------------------------------------------------------------------------
__launch_bounds__(256)
__global__ void aggregate2(const float* __restrict__ h2, const float* __restrict__ as2,
                           const float* __restrict__ ad2, const int* __restrict__ rowptr,
                           const int* __restrict__ esrc, const float* __restrict__ b2,
                           float* __restrict__ out, int N) {
    int wid = threadIdx.x >> 6, lane = threadIdx.x & 63;
    int node = blockIdx.x * 4 + wid;
    if (node >= N) return;
    float adn = ad2[node];
    float aself = leakys(as2[node] + adn);
    int start = rowptr[node], end = rowptr[node + 1];
    float m = aself;
    for (int e = start + lane; e < end; e += 64)
        m = fmaxf(m, leakys(as2[esrc[e]] + adn));
#pragma unroll
    for (int o = 1; o < 64; o <<= 1) m = fmaxf(m, __shfl_xor(m, o));
    float ssum = (lane == 0) ? __expf(aself - m) : 0.f;
    for (int e = start + lane; e < end; e += 64)
        ssum += __expf(leakys(as2[esrc[e]] + adn) - m);
#pragma unroll
    for (int o = 1; o < 64; o <<= 1) ssum += __shfl_xor(ssum, o);
    float inv = 1.f / (ssum + 1e-16f);
    float acc = __expf(aself - m) * inv * h2[(size_t)node * 64 + lane];
    for (int e = start; e < end; e++) {
        int s = esrc[e];
        acc += __expf(leakys(as2[s] + adn) - m) * inv * h2[(size_t)s * 64 + lane];
    }
    out[(size_t)node * 64 + lane] = acc + b2[lane];
}

// ---------------------------------------------------------------------------
extern "C" void kernel_launch(void* const* d_in, const int* in_sizes, int n_in,
                              void* d_out, int out_size, void* d_ws, size_t ws_size,
                              hipStream_t stream) {
    const float* x      = (const float*)d_in[0];
    const int*   ei     = (const int*)d_in[1];   // [2][E], int32
    const float* W1     = (const float*)d_in[2];
    const float* att_s1 = (const float*)d_in[3];
    const float* att_d1 = (const float*)d_in[4];
    const float* b1     = (const float*)d_in[5];
    const float* W2     = (const float*)d_in[6];
    const float* att_s2 = (const float*)d_in[7];
    const float* att_d2 = (const float*)d_in[8];
    const float* b2     = (const float*)d_in[9];

    const int N = in_sizes[0] / 128;
    const int E = in_sizes[1] / 2;

    char* ws = (char*)d_ws;
    size_t off = 0;
    auto alloc = [&](size_t bytes) -> void* {
        off = (off + 255) & ~(size_t)255;
        void* p = ws + off;
        off += bytes;
        return p;
    };
    float* h1     = (float*)alloc((size_t)N * 128 * 4);
    float* out1   = (float*)alloc((size_t)N * 128 * 4);
    float* as1    = (float*)alloc((size_t)N * 4 * 4);
    float* ad1    = (float*)alloc((size_t)N * 4 * 4);
    int*   rowptr = (int*)alloc((size_t)(N + 1) * 4);
    int*   counts = (int*)alloc((size_t)N * 4);
    int*   cursor = (int*)alloc((size_t)N * 4);
    const int nb = (N + 1023) / 1024;
    int*   bsums  = (int*)alloc((size_t)nb * 4);
    int*   esrc   = (int*)alloc((size_t)E * 4);
    // layer-2 buffers reuse h1's region (h1 dead after aggregate1)
    float* h2  = h1;
    float* as2 = (float*)((char*)h1 + (size_t)N * 64 * 4);
    float* ad2 = as2 + N;

    const int* srcIdx = ei;
    const int* dstIdx = ei + E;

    hipMemsetAsync(counts, 0, (size_t)N * 4, stream);

    gemm_k128<128><<<(N + 63) / 64, 256, 0, stream>>>(x, W1, h1, N);
    attdot1<<<(N + 1) / 2, 256, 0, stream>>>(h1, att_s1, att_d1, as1, ad1, N);

    count_k<<<(E + 255) / 256, 256, 0, stream>>>(dstIdx, counts, E);
    scan_block<<<nb, 256, 0, stream>>>(counts, rowptr, bsums, N);
    scan_sums<<<1, 256, 0, stream>>>(bsums, nb);
    add_offsets<<<(N + 1 + 255) / 256, 256, 0, stream>>>(rowptr, bsums, cursor, N, E);
    fill_k<<<(E + 255) / 256, 256, 0, stream>>>(srcIdx, dstIdx, cursor, esrc, E);

    aggregate1<<<(N + 3) / 4, 256, 0, stream>>>(h1, as1, ad1, rowptr, esrc, b1, out1, N);

    gemm_k128<64><<<(N + 127) / 128, 256, 0, stream>>>(out1, W2, h2, N);
    attdot2<<<(N + 3) / 4, 256, 0, stream>>>(h2, att_s2, att_d2, as2, ad2, N);

    aggregate2<<<(N + 3) / 4, 256, 0, stream>>>(h2, as2, ad2, rowptr, esrc, b2,
                                                (float*)d_out, N);
}

// Round 2
// 679.289 us; speedup vs baseline: 1.5085x; 1.5085x over previous
//
#include <hip/hip_runtime.h>
#include <hip/hip_bf16.h>

#define DEV static __device__ __forceinline__

typedef __attribute__((ext_vector_type(4))) float f32x4;
typedef __attribute__((ext_vector_type(8))) short bf16x8;

DEV float leakys(float v) { return v > 0.f ? v : 0.2f * v; }
DEV float4 add4(float4 a, float4 b) { return make_float4(a.x+b.x, a.y+b.y, a.z+b.z, a.w+b.w); }
DEV float4 sub4(float4 a, float4 b) { return make_float4(a.x-b.x, a.y-b.y, a.z-b.z, a.w-b.w); }
DEV float4 max4(float4 a, float4 b) { return make_float4(fmaxf(a.x,b.x), fmaxf(a.y,b.y), fmaxf(a.z,b.z), fmaxf(a.w,b.w)); }
DEV float4 leaky4(float4 v) { return make_float4(leakys(v.x), leakys(v.y), leakys(v.z), leakys(v.w)); }
DEV float4 exp4(float4 v) { return make_float4(__expf(v.x), __expf(v.y), __expf(v.z), __expf(v.w)); }

DEV ushort f2bf(float f) {
    union { float f; unsigned u; } v; v.f = f;
    unsigned u = v.u;
    unsigned r = (u + 0x7FFFu + ((u >> 16) & 1u)) >> 16;   // RNE
    return (ushort)r;
}
DEV float bf2f(ushort h) {
    union { unsigned u; float f; } v; v.u = ((unsigned)h) << 16;
    return v.f;
}

// ---------------------------------------------------------------------------
// One-time W prep: W[K=128][NC] f32 -> transposed bf16 hi/lo  Wt[n][k].
// ---------------------------------------------------------------------------
__global__ void prep_w(const float* __restrict__ W, ushort* __restrict__ Wth,
                       ushort* __restrict__ Wtl, int NC) {
    int i = blockIdx.x * 256 + threadIdx.x;
    if (i >= 128 * NC) return;
    int k = i / NC, n = i % NC;
    float v = W[i];
    ushort hi = f2bf(v);
    ushort lo = f2bf(v - bf2f(hi));
    Wth[n * 128 + k] = hi;
    Wtl[n * 128 + k] = lo;
}

// ---------------------------------------------------------------------------
// MFMA GEMM: C[N][NCOLS] = A[N][128] @ W[128][NCOLS], split-bf16 (3 MFMA).
// Block = 256 thr (4 waves), tile = 64 rows x NCOLS. Wave w owns n-cols
// [w*16*NT, ...). A staged to LDS as bf16 hi/lo with XOR swizzle.
// Fragment layout (m97-verified): lane l -> A[m=l&15][k=8*(l>>4)+j],
// B from Wt rows (k contiguous); C/D: col=l&15, row=4*(l>>4)+reg (m89).
// ---------------------------------------------------------------------------
template <int NCOLS>
__launch_bounds__(256, 2)
__global__ void gemm_mfma(const float* __restrict__ A, const ushort* __restrict__ Wth,
                          const ushort* __restrict__ Wtl, float* __restrict__ C, int N) {
    constexpr int NT = NCOLS / 64;          // 16-wide n-tiles per wave
    __shared__ ushort Xhi[64 * 128];
    __shared__ ushort Xlo[64 * 128];
    const int t = threadIdx.x;
    const int wv = t >> 6, l = t & 63;
    const int l15 = l & 15, lhi = l >> 4;
    const int row0 = blockIdx.x * 64;
    const int n0 = wv * 16 * NT;

    // stage 64x128 f32 -> bf16 hi/lo in LDS (swizzled)
    for (int i = t; i < 2048; i += 256) {
        int r = i >> 5, c4 = i & 31;
        int gr = row0 + r;
        float4 v = make_float4(0.f, 0.f, 0.f, 0.f);
        if (gr < N) v = ((const float4*)A)[(size_t)gr * 32 + c4];
        ushort4 hi, lo;
        hi.x = f2bf(v.x); lo.x = f2bf(v.x - bf2f(hi.x));
        hi.y = f2bf(v.y); lo.y = f2bf(v.y - bf2f(hi.y));
        hi.z = f2bf(v.z); lo.z = f2bf(v.z - bf2f(hi.z));
        hi.w = f2bf(v.w); lo.w = f2bf(v.w - bf2f(hi.w));
        int idx = (r * 128 + c4 * 4) ^ ((r & 7) << 3);
        *(ushort4*)&Xhi[idx] = hi;
        *(ushort4*)&Xlo[idx] = lo;
    }
    __syncthreads();

    f32x4 acc[4][NT];
#pragma unroll
    for (int mt = 0; mt < 4; mt++)
#pragma unroll
        for (int nt = 0; nt < NT; nt++) acc[mt][nt] = (f32x4){0.f, 0.f, 0.f, 0.f};

#pragma unroll
    for (int ks = 0; ks < 4; ks++) {
        bf16x8 ah[4], al[4];
#pragma unroll
        for (int mt = 0; mt < 4; mt++) {
            int row = mt * 16 + l15;
            int idx = (row * 128 + ks * 32 + lhi * 8) ^ ((row & 7) << 3);
            ah[mt] = *(const bf16x8*)&Xhi[idx];
            al[mt] = *(const bf16x8*)&Xlo[idx];
        }
#pragma unroll
        for (int nt = 0; nt < NT; nt++) {
            size_t wo = (size_t)(n0 + nt * 16 + l15) * 128 + ks * 32 + lhi * 8;
            bf16x8 bh = *(const bf16x8*)&Wth[wo];
            bf16x8 bl = *(const bf16x8*)&Wtl[wo];
#pragma unroll
            for (int mt = 0; mt < 4; mt++) {
                acc[mt][nt] = __builtin_amdgcn_mfma_f32_16x16x32_bf16(ah[mt], bh, acc[mt][nt], 0, 0, 0);
                acc[mt][nt] = __builtin_amdgcn_mfma_f32_16x16x32_bf16(ah[mt], bl, acc[mt][nt], 0, 0, 0);
                acc[mt][nt] = __builtin_amdgcn_mfma_f32_16x16x32_bf16(al[mt], bh, acc[mt][nt], 0, 0, 0);
            }
        }
    }
#pragma unroll
    for (int mt = 0; mt < 4; mt++) {
#pragma unroll
        for (int j = 0; j < 4; j++) {
            int gr = row0 + mt * 16 + lhi * 4 + j;
            if (gr < N) {
#pragma unroll
                for (int nt = 0; nt < NT; nt++)
                    C[(size_t)gr * NCOLS + n0 + nt * 16 + l15] = acc[mt][nt][j];
            }
        }
    }
}

// ---------------------------------------------------------------------------
// attention dot products
// ---------------------------------------------------------------------------
__global__ void attdot1(const float* __restrict__ h, const float* __restrict__ asrc,
                        const float* __restrict__ adst, float* __restrict__ as,
                        float* __restrict__ ad, int N) {
    int t = threadIdx.x;
    int node = blockIdx.x * 2 + (t >> 7);
    int j = t & 127;
    if (node >= N) return;
    float v = h[(size_t)node * 128 + j];
    float s = v * asrc[j];
    float d = v * adst[j];
#pragma unroll
    for (int o = 1; o < 32; o <<= 1) { s += __shfl_xor(s, o); d += __shfl_xor(d, o); }
    if ((j & 31) == 0) { int head = j >> 5; as[node * 4 + head] = s; ad[node * 4 + head] = d; }
}

__global__ void attdot2(const float* __restrict__ h, const float* __restrict__ asrc,
                        const float* __restrict__ adst, float* __restrict__ as,
                        float* __restrict__ ad, int N) {
    int t = threadIdx.x;
    int node = blockIdx.x * 4 + (t >> 6);
    int j = t & 63;
    if (node >= N) return;
    float v = h[(size_t)node * 64 + j];
    float s = v * asrc[j];
    float d = v * adst[j];
#pragma unroll
    for (int o = 1; o < 64; o <<= 1) { s += __shfl_xor(s, o); d += __shfl_xor(d, o); }
    if (j == 0) { as[node] = s; ad[node] = d; }
}

// ---------------------------------------------------------------------------
// CSR build: histogram -> 2-level exclusive scan -> fill
// ---------------------------------------------------------------------------
__global__ void count_k(const int* __restrict__ dstIdx, int* __restrict__ counts, int E) {
    int e = blockIdx.x * 256 + threadIdx.x;
    if (e < E) atomicAdd(&counts[dstIdx[e]], 1);
}

__global__ void scan_block(const int* __restrict__ in, int* __restrict__ out,
                           int* __restrict__ bsums, int n) {
    __shared__ int lds[256];
    int t = threadIdx.x;
    int base = blockIdx.x * 1024 + t * 4;
    int v0 = 0, v1 = 0, v2 = 0, v3 = 0;
    if (base + 0 < n) v0 = in[base + 0];
    if (base + 1 < n) v1 = in[base + 1];
    if (base + 2 < n) v2 = in[base + 2];
    if (base + 3 < n) v3 = in[base + 3];
    int tsum = v0 + v1 + v2 + v3;
    lds[t] = tsum;
    __syncthreads();
    int val = tsum;
    for (int o = 1; o < 256; o <<= 1) {
        int other = (t >= o) ? lds[t - o] : 0;
        __syncthreads();
        val += other; lds[t] = val;
        __syncthreads();
    }
    if (t == 255) bsums[blockIdx.x] = val;
    int run = val - tsum;
    if (base + 0 < n) out[base + 0] = run; run += v0;
    if (base + 1 < n) out[base + 1] = run; run += v1;
    if (base + 2 < n) out[base + 2] = run; run += v2;
    if (base + 3 < n) out[base + 3] = run;
}

__global__ void scan_sums(int* __restrict__ bsums, int nb) {
    __shared__ int lds[256];
    int t = threadIdx.x;
    int orig = (t < nb) ? bsums[t] : 0;
    lds[t] = orig;
    __syncthreads();
    int val = orig;
    for (int o = 1; o < 256; o <<= 1) {
        int other = (t >= o) ? lds[t - o] : 0;
        __syncthreads();
        val += other; lds[t] = val;
        __syncthreads();
    }
    if (t < nb) bsums[t] = val - orig;
}

__global__ void add_offsets(int* __restrict__ rowptr, const int* __restrict__ bsums,
                            int* __restrict__ cursor, int n, int total) {
    int i = blockIdx.x * 256 + threadIdx.x;
    if (i < n) {
        int v = rowptr[i] + bsums[i >> 10];
        rowptr[i] = v;
        cursor[i] = v;
    } else if (i == n) {
        rowptr[n] = total;
    }
}

__global__ void fill_k(const int* __restrict__ srcIdx, const int* __restrict__ dstIdx,
                       int* __restrict__ cursor, int* __restrict__ esrc, int E) {
    int e = blockIdx.x * 256 + threadIdx.x;
    if (e < E) {
        int pos = atomicAdd(&cursor[dstIdx[e]], 1);
        esrc[pos] = srcIdx[e];
    }
}

// ---------------------------------------------------------------------------
// Layer-1 aggregation (one wave per dst node)
// ---------------------------------------------------------------------------
__launch_bounds__(256)
__global__ void aggregate1(const float* __restrict__ h1, const float* __restrict__ as1,
                           const float* __restrict__ ad1, const int* __restrict__ rowptr,
                           const int* __restrict__ esrc, const float* __restrict__ b1,
                           float* __restrict__ out1, int N) {
    int wid = threadIdx.x >> 6, lane = threadIdx.x & 63;
    int node = blockIdx.x * 4 + wid;
    if (node >= N) return;
    float4 asn = *(const float4*)&as1[node * 4];
    float4 adn = *(const float4*)&ad1[node * 4];
    float4 aself = leaky4(add4(asn, adn));
    int start = rowptr[node], end = rowptr[node + 1];

    float4 m = aself;
    for (int e = start + lane; e < end; e += 64) {
        float4 a = *(const float4*)&as1[esrc[e] * 4];
        m = max4(m, leaky4(add4(a, adn)));
    }
#pragma unroll
    for (int o = 1; o < 64; o <<= 1) {
        m.x = fmaxf(m.x, __shfl_xor(m.x, o));
        m.y = fmaxf(m.y, __shfl_xor(m.y, o));
        m.z = fmaxf(m.z, __shfl_xor(m.z, o));
        m.w = fmaxf(m.w, __shfl_xor(m.w, o));
    }
    float4 ssum = make_float4(0.f, 0.f, 0.f, 0.f);
    if (lane == 0) ssum = exp4(sub4(aself, m));
    for (int e = start + lane; e < end; e += 64) {
        float4 a = leaky4(add4(*(const float4*)&as1[esrc[e] * 4], adn));
        ssum = add4(ssum, exp4(sub4(a, m)));
    }
#pragma unroll
    for (int o = 1; o < 64; o <<= 1) {
        ssum.x += __shfl_xor(ssum.x, o);
        ssum.y += __shfl_xor(ssum.y, o);
        ssum.z += __shfl_xor(ssum.z, o);
        ssum.w += __shfl_xor(ssum.w, o);
    }
    int hA = lane >> 5;
    float mA = hA ? m.y : m.x;
    float mB = hA ? m.w : m.z;
    float invA = 1.f / ((hA ? ssum.y : ssum.x) + 1e-16f);
    float invB = 1.f / ((hA ? ssum.w : ssum.z) + 1e-16f);
    float adA = hA ? adn.y : adn.x;
    float adB = hA ? adn.w : adn.z;
    float selfA = hA ? aself.y : aself.x;
    float selfB = hA ? aself.w : aself.z;
    int j0 = lane, j1 = lane + 64;
    const float* hp = h1 + (size_t)node * 128;
    float acc0 = __expf(selfA - mA) * invA * hp[j0];
    float acc1 = __expf(selfB - mB) * invB * hp[j1];
    for (int e = start; e < end; e++) {
        int s = esrc[e];
        const float* hq = h1 + (size_t)s * 128;
        float aA = leakys(as1[s * 4 + hA] + adA);
        float aB = leakys(as1[s * 4 + 2 + hA] + adB);
        acc0 += __expf(aA - mA) * invA * hq[j0];
        acc1 += __expf(aB - mB) * invB * hq[j1];
    }
    float o0 = acc0 + b1[j0];
    float o1 = acc1 + b1[j1];
    out1[(size_t)node * 128 + j0] = fmaxf(o0, 0.f);
    out1[(size_t)node * 128 + j1] = fmaxf(o1, 0.f);
}

// ---------------------------------------------------------------------------
// Layer-2 aggregation (H=1, C=64)
// ---------------------------------------------------------------------------
__launch_bounds__(256)
__global__ void aggregate2(const float* __restrict__ h2, const float* __restrict__ as2,
                           const float* __restrict__ ad2, const int* __restrict__ rowptr,
                           const int* __restrict__ esrc, const float* __restrict__ b2,
                           float* __restrict__ out, int N) {
    int wid = threadIdx.x >> 6, lane = threadIdx.x & 63;
    int node = blockIdx.x * 4 + wid;
    if (node >= N) return;
    float adn = ad2[node];
    float aself = leakys(as2[node] + adn);
    int start = rowptr[node], end = rowptr[node + 1];
    float m = aself;
    for (int e = start + lane; e < end; e += 64)
        m = fmaxf(m, leakys(as2[esrc[e]] + adn));
#pragma unroll
    for (int o = 1; o < 64; o <<= 1) m = fmaxf(m, __shfl_xor(m, o));
    float ssum = (lane == 0) ? __expf(aself - m) : 0.f;
    for (int e = start + lane; e < end; e += 64)
        ssum += __expf(leakys(as2[esrc[e]] + adn) - m);
#pragma unroll
    for (int o = 1; o < 64; o <<= 1) ssum += __shfl_xor(ssum, o);
    float inv = 1.f / (ssum + 1e-16f);
    float acc = __expf(aself - m) * inv * h2[(size_t)node * 64 + lane];
    for (int e = start; e < end; e++) {
        int s = esrc[e];
        acc += __expf(leakys(as2[s] + adn) - m) * inv * h2[(size_t)s * 64 + lane];
    }
    out[(size_t)node * 64 + lane] = acc + b2[lane];
}

// ---------------------------------------------------------------------------
extern "C" void kernel_launch(void* const* d_in, const int* in_sizes, int n_in,
                              void* d_out, int out_size, void* d_ws, size_t ws_size,
                              hipStream_t stream) {
    const float* x      = (const float*)d_in[0];
    const int*   ei     = (const int*)d_in[1];
    const float* W1     = (const float*)d_in[2];
    const float* att_s1 = (const float*)d_in[3];
    const float* att_d1 = (const float*)d_in[4];
    const float* b1     = (const float*)d_in[5];
    const float* W2     = (const float*)d_in[6];
    const float* att_s2 = (const float*)d_in[7];
    const float* att_d2 = (const float*)d_in[8];
    const float* b2     = (const float*)d_in[9];

    const int N = in_sizes[0] / 128;
    const int E = in_sizes[1] / 2;

    char* ws = (char*)d_ws;
    size_t off = 0;
    auto alloc = [&](size_t bytes) -> void* {
        off = (off + 255) & ~(size_t)255;
        void* p = ws + off;
        off += bytes;
        return p;
    };
    float* h1     = (float*)alloc((size_t)N * 128 * 4);
    float* out1   = (float*)alloc((size_t)N * 128 * 4);
    float* as1    = (float*)alloc((size_t)N * 4 * 4);
    float* ad1    = (float*)alloc((size_t)N * 4 * 4);
    int*   rowptr = (int*)alloc((size_t)(N + 1) * 4);
    int*   counts = (int*)alloc((size_t)N * 4);
    int*   cursor = (int*)alloc((size_t)N * 4);
    const int nb = (N + 1023) / 1024;
    int*   bsums  = (int*)alloc((size_t)nb * 4);
    int*   esrc   = (int*)alloc((size_t)E * 4);
    ushort* Wt1h  = (ushort*)alloc(128 * 128 * 2);
    ushort* Wt1l  = (ushort*)alloc(128 * 128 * 2);
    ushort* Wt2h  = (ushort*)alloc(64 * 128 * 2);
    ushort* Wt2l  = (ushort*)alloc(64 * 128 * 2);
    float* h2  = h1;
    float* as2 = (float*)((char*)h1 + (size_t)N * 64 * 4);
    float* ad2 = as2 + N;

    const int* srcIdx = ei;
    const int* dstIdx = ei + E;

    hipMemsetAsync(counts, 0, (size_t)N * 4, stream);

    prep_w<<<64, 256, 0, stream>>>(W1, Wt1h, Wt1l, 128);
    prep_w<<<32, 256, 0, stream>>>(W2, Wt2h, Wt2l, 64);

    gemm_mfma<128><<<(N + 63) / 64, 256, 0, stream>>>(x, Wt1h, Wt1l, h1, N);
    attdot1<<<(N + 1) / 2, 256, 0, stream>>>(h1, att_s1, att_d1, as1, ad1, N);

    count_k<<<(E + 255) / 256, 256, 0, stream>>>(dstIdx, counts, E);
    scan_block<<<nb, 256, 0, stream>>>(counts, rowptr, bsums, N);
    scan_sums<<<1, 256, 0, stream>>>(bsums, nb);
    add_offsets<<<(N + 1 + 255) / 256, 256, 0, stream>>>(rowptr, bsums, cursor, N, E);
    fill_k<<<(E + 255) / 256, 256, 0, stream>>>(srcIdx, dstIdx, cursor, esrc, E);

    aggregate1<<<(N + 3) / 4, 256, 0, stream>>>(h1, as1, ad1, rowptr, esrc, b1, out1, N);

    gemm_mfma<64><<<(N + 63) / 64, 256, 0, stream>>>(out1, Wt2h, Wt2l, h2, N);
    attdot2<<<(N + 3) / 4, 256, 0, stream>>>(h2, att_s2, att_d2, as2, ad2, N);

    aggregate2<<<(N + 3) / 4, 256, 0, stream>>>(h2, as2, ad2, rowptr, esrc, b2,
                                                (float*)d_out, N);
}

// Round 3
// 505.172 us; speedup vs baseline: 2.0284x; 1.3447x over previous
//
#include <hip/hip_runtime.h>
#include <hip/hip_bf16.h>

#define DEV static __device__ __forceinline__

typedef __attribute__((ext_vector_type(4))) float f32x4;
typedef __attribute__((ext_vector_type(8))) short bf16x8;

DEV float leakys(float v) { return v > 0.f ? v : 0.2f * v; }
DEV float4 add4(float4 a, float4 b) { return make_float4(a.x+b.x, a.y+b.y, a.z+b.z, a.w+b.w); }
DEV float4 leaky4(float4 v) { return make_float4(leakys(v.x), leakys(v.y), leakys(v.z), leakys(v.w)); }
DEV float4 exp4(float4 v) { return make_float4(__expf(v.x), __expf(v.y), __expf(v.z), __expf(v.w)); }
DEV float pick4(float4 v, int i) {
    float r = v.x;
    r = (i == 1) ? v.y : r;
    r = (i == 2) ? v.z : r;
    r = (i == 3) ? v.w : r;
    return r;
}

DEV ushort f2bf(float f) {
    union { float f; unsigned u; } v; v.f = f;
    unsigned u = v.u;
    unsigned r = (u + 0x7FFFu + ((u >> 16) & 1u)) >> 16;   // RNE
    return (ushort)r;
}
DEV float bf2f(ushort h) {
    union { unsigned u; float f; } v; v.u = ((unsigned)h) << 16;
    return v.f;
}

// ---------------------------------------------------------------------------
// One-time W prep: W[K=128][NC] f32 -> transposed bf16 hi/lo  Wt[n][k].
// ---------------------------------------------------------------------------
__global__ void prep_w(const float* __restrict__ W, ushort* __restrict__ Wth,
                       ushort* __restrict__ Wtl, int NC) {
    int i = blockIdx.x * 256 + threadIdx.x;
    if (i >= 128 * NC) return;
    int k = i / NC, n = i % NC;
    float v = W[i];
    ushort hi = f2bf(v);
    ushort lo = f2bf(v - bf2f(hi));
    Wth[n * 128 + k] = hi;
    Wtl[n * 128 + k] = lo;
}

// ---------------------------------------------------------------------------
// MFMA GEMM: C[N][NCOLS] = A[N][128] @ W[128][NCOLS], split-bf16 (3 MFMA).
// ---------------------------------------------------------------------------
template <int NCOLS>
__launch_bounds__(256, 2)
__global__ void gemm_mfma(const float* __restrict__ A, const ushort* __restrict__ Wth,
                          const ushort* __restrict__ Wtl, float* __restrict__ C, int N) {
    constexpr int NT = NCOLS / 64;          // 16-wide n-tiles per wave
    __shared__ ushort Xhi[64 * 128];
    __shared__ ushort Xlo[64 * 128];
    const int t = threadIdx.x;
    const int wv = t >> 6, l = t & 63;
    const int l15 = l & 15, lhi = l >> 4;
    const int row0 = blockIdx.x * 64;
    const int n0 = wv * 16 * NT;

    for (int i = t; i < 2048; i += 256) {
        int r = i >> 5, c4 = i & 31;
        int gr = row0 + r;
        float4 v = make_float4(0.f, 0.f, 0.f, 0.f);
        if (gr < N) v = ((const float4*)A)[(size_t)gr * 32 + c4];
        ushort4 hi, lo;
        hi.x = f2bf(v.x); lo.x = f2bf(v.x - bf2f(hi.x));
        hi.y = f2bf(v.y); lo.y = f2bf(v.y - bf2f(hi.y));
        hi.z = f2bf(v.z); lo.z = f2bf(v.z - bf2f(hi.z));
        hi.w = f2bf(v.w); lo.w = f2bf(v.w - bf2f(hi.w));
        int idx = (r * 128 + c4 * 4) ^ ((r & 7) << 3);
        *(ushort4*)&Xhi[idx] = hi;
        *(ushort4*)&Xlo[idx] = lo;
    }
    __syncthreads();

    f32x4 acc[4][NT];
#pragma unroll
    for (int mt = 0; mt < 4; mt++)
#pragma unroll
        for (int nt = 0; nt < NT; nt++) acc[mt][nt] = (f32x4){0.f, 0.f, 0.f, 0.f};

#pragma unroll
    for (int ks = 0; ks < 4; ks++) {
        bf16x8 ah[4], al[4];
#pragma unroll
        for (int mt = 0; mt < 4; mt++) {
            int row = mt * 16 + l15;
            int idx = (row * 128 + ks * 32 + lhi * 8) ^ ((row & 7) << 3);
            ah[mt] = *(const bf16x8*)&Xhi[idx];
            al[mt] = *(const bf16x8*)&Xlo[idx];
        }
#pragma unroll
        for (int nt = 0; nt < NT; nt++) {
            size_t wo = (size_t)(n0 + nt * 16 + l15) * 128 + ks * 32 + lhi * 8;
            bf16x8 bh = *(const bf16x8*)&Wth[wo];
            bf16x8 bl = *(const bf16x8*)&Wtl[wo];
#pragma unroll
            for (int mt = 0; mt < 4; mt++) {
                acc[mt][nt] = __builtin_amdgcn_mfma_f32_16x16x32_bf16(ah[mt], bh, acc[mt][nt], 0, 0, 0);
                acc[mt][nt] = __builtin_amdgcn_mfma_f32_16x16x32_bf16(ah[mt], bl, acc[mt][nt], 0, 0, 0);
                acc[mt][nt] = __builtin_amdgcn_mfma_f32_16x16x32_bf16(al[mt], bh, acc[mt][nt], 0, 0, 0);
            }
        }
    }
#pragma unroll
    for (int mt = 0; mt < 4; mt++) {
#pragma unroll
        for (int j = 0; j < 4; j++) {
            int gr = row0 + mt * 16 + lhi * 4 + j;
            if (gr < N) {
#pragma unroll
                for (int nt = 0; nt < NT; nt++)
                    C[(size_t)gr * NCOLS + n0 + nt * 16 + l15] = acc[mt][nt][j];
            }
        }
    }
}

// ---------------------------------------------------------------------------
// attention dot products
// ---------------------------------------------------------------------------
__global__ void attdot1(const float* __restrict__ h, const float* __restrict__ asrc,
                        const float* __restrict__ adst, float* __restrict__ as,
                        float* __restrict__ ad, int N) {
    int t = threadIdx.x;
    int node = blockIdx.x * 2 + (t >> 7);
    int j = t & 127;
    if (node >= N) return;
    float v = h[(size_t)node * 128 + j];
    float s = v * asrc[j];
    float d = v * adst[j];
#pragma unroll
    for (int o = 1; o < 32; o <<= 1) { s += __shfl_xor(s, o); d += __shfl_xor(d, o); }
    if ((j & 31) == 0) { int head = j >> 5; as[node * 4 + head] = s; ad[node * 4 + head] = d; }
}

__global__ void attdot2(const float* __restrict__ h, const float* __restrict__ asrc,
                        const float* __restrict__ adst, float* __restrict__ as,
                        float* __restrict__ ad, int N) {
    int t = threadIdx.x;
    int node = blockIdx.x * 4 + (t >> 6);
    int j = t & 63;
    if (node >= N) return;
    float v = h[(size_t)node * 64 + j];
    float s = v * asrc[j];
    float d = v * adst[j];
#pragma unroll
    for (int o = 1; o < 64; o <<= 1) { s += __shfl_xor(s, o); d += __shfl_xor(d, o); }
    if (j == 0) { as[node] = s; ad[node] = d; }
}

// ---------------------------------------------------------------------------
// CSR build: histogram -> 2-level exclusive scan -> fill
// ---------------------------------------------------------------------------
__global__ void count_k(const int* __restrict__ dstIdx, int* __restrict__ counts, int E) {
    int e = blockIdx.x * 256 + threadIdx.x;
    if (e < E) atomicAdd(&counts[dstIdx[e]], 1);
}

__global__ void scan_block(const int* __restrict__ in, int* __restrict__ out,
                           int* __restrict__ bsums, int n) {
    __shared__ int lds[256];
    int t = threadIdx.x;
    int base = blockIdx.x * 1024 + t * 4;
    int v0 = 0, v1 = 0, v2 = 0, v3 = 0;
    if (base + 0 < n) v0 = in[base + 0];
    if (base + 1 < n) v1 = in[base + 1];
    if (base + 2 < n) v2 = in[base + 2];
    if (base + 3 < n) v3 = in[base + 3];
    int tsum = v0 + v1 + v2 + v3;
    lds[t] = tsum;
    __syncthreads();
    int val = tsum;
    for (int o = 1; o < 256; o <<= 1) {
        int other = (t >= o) ? lds[t - o] : 0;
        __syncthreads();
        val += other; lds[t] = val;
        __syncthreads();
    }
    if (t == 255) bsums[blockIdx.x] = val;
    int run = val - tsum;
    if (base + 0 < n) out[base + 0] = run; run += v0;
    if (base + 1 < n) out[base + 1] = run; run += v1;
    if (base + 2 < n) out[base + 2] = run; run += v2;
    if (base + 3 < n) out[base + 3] = run;
}

__global__ void scan_sums(int* __restrict__ bsums, int nb) {
    __shared__ int lds[256];
    int t = threadIdx.x;
    int orig = (t < nb) ? bsums[t] : 0;
    lds[t] = orig;
    __syncthreads();
    int val = orig;
    for (int o = 1; o < 256; o <<= 1) {
        int other = (t >= o) ? lds[t - o] : 0;
        __syncthreads();
        val += other; lds[t] = val;
        __syncthreads();
    }
    if (t < nb) bsums[t] = val - orig;
}

__global__ void add_offsets(int* __restrict__ rowptr, const int* __restrict__ bsums,
                            int* __restrict__ cursor, int n, int total) {
    int i = blockIdx.x * 256 + threadIdx.x;
    if (i < n) {
        int v = rowptr[i] + bsums[i >> 10];
        rowptr[i] = v;
        cursor[i] = v;
    } else if (i == n) {
        rowptr[n] = total;
    }
}

__global__ void fill_k(const int* __restrict__ srcIdx, const int* __restrict__ dstIdx,
                       int* __restrict__ cursor, int* __restrict__ esrc, int E) {
    int e = blockIdx.x * 256 + threadIdx.x;
    if (e < E) {
        int pos = atomicAdd(&cursor[dstIdx[e]], 1);
        esrc[pos] = srcIdx[e];
    }
}

// ---------------------------------------------------------------------------
// Layer-1 aggregation. One wave per dst node. Phase B: lane-parallel edge
// weights w=exp(leaky(as[s]+ad[n])) (m=0; softmax shift-invariant, scores
// bounded), stored to ew[e][4]; denom reduced in regs, inv deferred to
// epilogue. Phase C: 32 lanes x float4 = one 512B h-row; 2 edges/iter.
// ---------------------------------------------------------------------------
__launch_bounds__(256)
__global__ void aggregate1(const float* __restrict__ h1, const float* __restrict__ as1,
                           const float* __restrict__ ad1, const int* __restrict__ rowptr,
                           const int* __restrict__ esrc, float* __restrict__ ew,
                           const float* __restrict__ b1, float* __restrict__ out1, int N) {
    int wid = threadIdx.x >> 6, lane = threadIdx.x & 63;
    int node = blockIdx.x * 4 + wid;
    if (node >= N) return;
    float4 asn = *(const float4*)&as1[node * 4];
    float4 adn = *(const float4*)&ad1[node * 4];
    float4 selfw = exp4(leaky4(add4(asn, adn)));
    int start = rowptr[node], end = rowptr[node + 1];

    // phase B: per-edge weights + denominator
    float4 ssum = make_float4(0.f, 0.f, 0.f, 0.f);
    for (int e = start + lane; e < end; e += 64) {
        int s = esrc[e];
        float4 w = exp4(leaky4(add4(*(const float4*)&as1[s * 4], adn)));
        *(float4*)&ew[(size_t)e * 4] = w;
        ssum = add4(ssum, w);
    }
#pragma unroll
    for (int o = 1; o < 64; o <<= 1) {
        ssum.x += __shfl_xor(ssum.x, o);
        ssum.y += __shfl_xor(ssum.y, o);
        ssum.z += __shfl_xor(ssum.z, o);
        ssum.w += __shfl_xor(ssum.w, o);
    }
    float4 denom = add4(ssum, selfw);
    int half = lane >> 5, c = lane & 31, hA = c >> 3;
    float inv = 1.f / (pick4(denom, hA) + 1e-16f);
    float sw = pick4(selfw, hA);

    // phase C: pure gather-FMA, 2 edges per iteration
    float4 acc = make_float4(0.f, 0.f, 0.f, 0.f);
#pragma unroll 4
    for (int e = start; e < end; e += 2) {
        int em = e + half;
        int s = 0; float w = 0.f;
        if (em < end) { s = esrc[em]; w = ew[(size_t)em * 4 + hA]; }
        float4 hv = *(const float4*)&h1[(size_t)s * 128 + c * 4];
        acc.x += w * hv.x; acc.y += w * hv.y; acc.z += w * hv.z; acc.w += w * hv.w;
    }
    acc.x += __shfl_xor(acc.x, 32);
    acc.y += __shfl_xor(acc.y, 32);
    acc.z += __shfl_xor(acc.z, 32);
    acc.w += __shfl_xor(acc.w, 32);
    if (half == 0) {
        float4 hv = *(const float4*)&h1[(size_t)node * 128 + c * 4];
        float4 bb = *(const float4*)&b1[c * 4];
        float4 o;
        o.x = fmaxf((acc.x + sw * hv.x) * inv + bb.x, 0.f);
        o.y = fmaxf((acc.y + sw * hv.y) * inv + bb.y, 0.f);
        o.z = fmaxf((acc.z + sw * hv.z) * inv + bb.z, 0.f);
        o.w = fmaxf((acc.w + sw * hv.w) * inv + bb.w, 0.f);
        *(float4*)&out1[(size_t)node * 128 + c * 4] = o;
    }
}

// ---------------------------------------------------------------------------
// Layer-2 aggregation (H=1, C=64): 16 lanes x float4 = one 256B row; 4 edges
// per iteration.
// ---------------------------------------------------------------------------
__launch_bounds__(256)
__global__ void aggregate2(const float* __restrict__ h2, const float* __restrict__ as2,
                           const float* __restrict__ ad2, const int* __restrict__ rowptr,
                           const int* __restrict__ esrc, float* __restrict__ ew,
                           const float* __restrict__ b2, float* __restrict__ out, int N) {
    int wid = threadIdx.x >> 6, lane = threadIdx.x & 63;
    int node = blockIdx.x * 4 + wid;
    if (node >= N) return;
    float adn = ad2[node];
    float selfw = __expf(leakys(as2[node] + adn));
    int start = rowptr[node], end = rowptr[node + 1];

    float ssum = 0.f;
    for (int e = start + lane; e < end; e += 64) {
        int s = esrc[e];
        float w = __expf(leakys(as2[s] + adn));
        ew[e] = w;
        ssum += w;
    }
#pragma unroll
    for (int o = 1; o < 64; o <<= 1) ssum += __shfl_xor(ssum, o);
    float inv = 1.f / (ssum + selfw + 1e-16f);
    int q = lane >> 4, c = lane & 15;

    float4 acc = make_float4(0.f, 0.f, 0.f, 0.f);
#pragma unroll 4
    for (int e = start; e < end; e += 4) {
        int em = e + q;
        int s = 0; float w = 0.f;
        if (em < end) { s = esrc[em]; w = ew[em]; }
        float4 hv = *(const float4*)&h2[(size_t)s * 64 + c * 4];
        acc.x += w * hv.x; acc.y += w * hv.y; acc.z += w * hv.z; acc.w += w * hv.w;
    }
#pragma unroll
    for (int o = 16; o < 64; o <<= 1) {
        acc.x += __shfl_xor(acc.x, o);
        acc.y += __shfl_xor(acc.y, o);
        acc.z += __shfl_xor(acc.z, o);
        acc.w += __shfl_xor(acc.w, o);
    }
    if (lane < 16) {
        float4 hv = *(const float4*)&h2[(size_t)node * 64 + c * 4];
        float4 bb = *(const float4*)&b2[c * 4];
        float4 o4;
        o4.x = (acc.x + selfw * hv.x) * inv + bb.x;
        o4.y = (acc.y + selfw * hv.y) * inv + bb.y;
        o4.z = (acc.z + selfw * hv.z) * inv + bb.z;
        o4.w = (acc.w + selfw * hv.w) * inv + bb.w;
        *(float4*)&out[(size_t)node * 64 + c * 4] = o4;
    }
}

// ---------------------------------------------------------------------------
extern "C" void kernel_launch(void* const* d_in, const int* in_sizes, int n_in,
                              void* d_out, int out_size, void* d_ws, size_t ws_size,
                              hipStream_t stream) {
    const float* x      = (const float*)d_in[0];
    const int*   ei     = (const int*)d_in[1];
    const float* W1     = (const float*)d_in[2];
    const float* att_s1 = (const float*)d_in[3];
    const float* att_d1 = (const float*)d_in[4];
    const float* b1     = (const float*)d_in[5];
    const float* W2     = (const float*)d_in[6];
    const float* att_s2 = (const float*)d_in[7];
    const float* att_d2 = (const float*)d_in[8];
    const float* b2     = (const float*)d_in[9];

    const int N = in_sizes[0] / 128;
    const int E = in_sizes[1] / 2;

    char* ws = (char*)d_ws;
    size_t off = 0;
    auto alloc = [&](size_t bytes) -> void* {
        off = (off + 255) & ~(size_t)255;
        void* p = ws + off;
        off += bytes;
        return p;
    };
    float* h1     = (float*)alloc((size_t)N * 128 * 4);
    float* out1   = (float*)alloc((size_t)N * 128 * 4);
    float* as1    = (float*)alloc((size_t)N * 4 * 4);
    float* ad1    = (float*)alloc((size_t)N * 4 * 4);
    int*   rowptr = (int*)alloc((size_t)(N + 1) * 4);
    int*   counts = (int*)alloc((size_t)N * 4);
    int*   cursor = (int*)alloc((size_t)N * 4);
    const int nb = (N + 1023) / 1024;
    int*   bsums  = (int*)alloc((size_t)nb * 4);
    int*   esrc   = (int*)alloc((size_t)E * 4);
    float* ew1    = (float*)alloc((size_t)E * 4 * 4);
    ushort* Wt1h  = (ushort*)alloc(128 * 128 * 2);
    ushort* Wt1l  = (ushort*)alloc(128 * 128 * 2);
    ushort* Wt2h  = (ushort*)alloc(64 * 128 * 2);
    ushort* Wt2l  = (ushort*)alloc(64 * 128 * 2);
    float* h2  = h1;                                   // h1 dead after aggregate1
    float* as2 = (float*)((char*)h1 + (size_t)N * 64 * 4);
    float* ad2 = as2 + N;
    float* ew2 = ew1;                                  // ew1 dead after aggregate1

    const int* srcIdx = ei;
    const int* dstIdx = ei + E;

    hipMemsetAsync(counts, 0, (size_t)N * 4, stream);

    prep_w<<<64, 256, 0, stream>>>(W1, Wt1h, Wt1l, 128);
    prep_w<<<32, 256, 0, stream>>>(W2, Wt2h, Wt2l, 64);

    gemm_mfma<128><<<(N + 63) / 64, 256, 0, stream>>>(x, Wt1h, Wt1l, h1, N);
    attdot1<<<(N + 1) / 2, 256, 0, stream>>>(h1, att_s1, att_d1, as1, ad1, N);

    count_k<<<(E + 255) / 256, 256, 0, stream>>>(dstIdx, counts, E);
    scan_block<<<nb, 256, 0, stream>>>(counts, rowptr, bsums, N);
    scan_sums<<<1, 256, 0, stream>>>(bsums, nb);
    add_offsets<<<(N + 1 + 255) / 256, 256, 0, stream>>>(rowptr, bsums, cursor, N, E);
    fill_k<<<(E + 255) / 256, 256, 0, stream>>>(srcIdx, dstIdx, cursor, esrc, E);

    aggregate1<<<(N + 3) / 4, 256, 0, stream>>>(h1, as1, ad1, rowptr, esrc, ew1, b1, out1, N);

    gemm_mfma<64><<<(N + 63) / 64, 256, 0, stream>>>(out1, Wt2h, Wt2l, h2, N);
    attdot2<<<(N + 3) / 4, 256, 0, stream>>>(h2, att_s2, att_d2, as2, ad2, N);

    aggregate2<<<(N + 3) / 4, 256, 0, stream>>>(h2, as2, ad2, rowptr, esrc, ew2, b2,
                                                (float*)d_out, N);
}

// Round 4
// 460.241 us; speedup vs baseline: 2.2264x; 1.0976x over previous
//
#include <hip/hip_runtime.h>
#include <hip/hip_bf16.h>

#define DEV static __device__ __forceinline__

typedef __attribute__((ext_vector_type(4))) float f32x4;
typedef __attribute__((ext_vector_type(8))) short bf16x8;
typedef __attribute__((ext_vector_type(8))) _Float16 half8;

DEV float leakys(float v) { return v > 0.f ? v : 0.2f * v; }
DEV float4 add4(float4 a, float4 b) { return make_float4(a.x+b.x, a.y+b.y, a.z+b.z, a.w+b.w); }
DEV float4 leaky4(float4 v) { return make_float4(leakys(v.x), leakys(v.y), leakys(v.z), leakys(v.w)); }
DEV float4 exp4(float4 v) { return make_float4(__expf(v.x), __expf(v.y), __expf(v.z), __expf(v.w)); }
DEV float pick4(float4 v, int i) {
    float r = v.x;
    r = (i == 1) ? v.y : r;
    r = (i == 2) ? v.z : r;
    r = (i == 3) ? v.w : r;
    return r;
}

DEV ushort f2bf(float f) {
    union { float f; unsigned u; } v; v.f = f;
    unsigned u = v.u;
    unsigned r = (u + 0x7FFFu + ((u >> 16) & 1u)) >> 16;   // RNE
    return (ushort)r;
}
DEV float bf2f(ushort h) {
    union { unsigned u; float f; } v; v.u = ((unsigned)h) << 16;
    return v.f;
}
DEV ushort f2h(float f) {
    union { _Float16 h; ushort u; } v;
    v.h = (_Float16)f;
    return v.u;
}

// ---------------------------------------------------------------------------
// One-time W prep: W[K=128][NC] f32 -> transposed bf16 hi/lo  Wt[n][k].
// ---------------------------------------------------------------------------
__global__ void prep_w(const float* __restrict__ W, ushort* __restrict__ Wth,
                       ushort* __restrict__ Wtl, int NC) {
    int i = blockIdx.x * 256 + threadIdx.x;
    if (i >= 128 * NC) return;
    int k = i / NC, n = i % NC;
    float v = W[i];
    ushort hi = f2bf(v);
    ushort lo = f2bf(v - bf2f(hi));
    Wth[n * 128 + k] = hi;
    Wtl[n * 128 + k] = lo;
}

// ---------------------------------------------------------------------------
// MFMA GEMM: C[N][NCOLS] = A[N][128] @ W[128][NCOLS], split-bf16 (3 MFMA).
// Epilogue also writes an fp16 copy (C16) used by the gather kernels.
// ---------------------------------------------------------------------------
template <int NCOLS>
__launch_bounds__(256, 2)
__global__ void gemm_mfma(const float* __restrict__ A, const ushort* __restrict__ Wth,
                          const ushort* __restrict__ Wtl, float* __restrict__ C,
                          ushort* __restrict__ C16, int N) {
    constexpr int NT = NCOLS / 64;          // 16-wide n-tiles per wave
    __shared__ ushort Xhi[64 * 128];
    __shared__ ushort Xlo[64 * 128];
    const int t = threadIdx.x;
    const int wv = t >> 6, l = t & 63;
    const int l15 = l & 15, lhi = l >> 4;
    const int row0 = blockIdx.x * 64;
    const int n0 = wv * 16 * NT;

    for (int i = t; i < 2048; i += 256) {
        int r = i >> 5, c4 = i & 31;
        int gr = row0 + r;
        float4 v = make_float4(0.f, 0.f, 0.f, 0.f);
        if (gr < N) v = ((const float4*)A)[(size_t)gr * 32 + c4];
        ushort4 hi, lo;
        hi.x = f2bf(v.x); lo.x = f2bf(v.x - bf2f(hi.x));
        hi.y = f2bf(v.y); lo.y = f2bf(v.y - bf2f(hi.y));
        hi.z = f2bf(v.z); lo.z = f2bf(v.z - bf2f(hi.z));
        hi.w = f2bf(v.w); lo.w = f2bf(v.w - bf2f(hi.w));
        int idx = (r * 128 + c4 * 4) ^ ((r & 7) << 3);
        *(ushort4*)&Xhi[idx] = hi;
        *(ushort4*)&Xlo[idx] = lo;
    }
    __syncthreads();

    f32x4 acc[4][NT];
#pragma unroll
    for (int mt = 0; mt < 4; mt++)
#pragma unroll
        for (int nt = 0; nt < NT; nt++) acc[mt][nt] = (f32x4){0.f, 0.f, 0.f, 0.f};

#pragma unroll
    for (int ks = 0; ks < 4; ks++) {
        bf16x8 ah[4], al[4];
#pragma unroll
        for (int mt = 0; mt < 4; mt++) {
            int row = mt * 16 + l15;
            int idx = (row * 128 + ks * 32 + lhi * 8) ^ ((row & 7) << 3);
            ah[mt] = *(const bf16x8*)&Xhi[idx];
            al[mt] = *(const bf16x8*)&Xlo[idx];
        }
#pragma unroll
        for (int nt = 0; nt < NT; nt++) {
            size_t wo = (size_t)(n0 + nt * 16 + l15) * 128 + ks * 32 + lhi * 8;
            bf16x8 bh = *(const bf16x8*)&Wth[wo];
            bf16x8 bl = *(const bf16x8*)&Wtl[wo];
#pragma unroll
            for (int mt = 0; mt < 4; mt++) {
                acc[mt][nt] = __builtin_amdgcn_mfma_f32_16x16x32_bf16(ah[mt], bh, acc[mt][nt], 0, 0, 0);
                acc[mt][nt] = __builtin_amdgcn_mfma_f32_16x16x32_bf16(ah[mt], bl, acc[mt][nt], 0, 0, 0);
                acc[mt][nt] = __builtin_amdgcn_mfma_f32_16x16x32_bf16(al[mt], bh, acc[mt][nt], 0, 0, 0);
            }
        }
    }
#pragma unroll
    for (int mt = 0; mt < 4; mt++) {
#pragma unroll
        for (int j = 0; j < 4; j++) {
            int gr = row0 + mt * 16 + lhi * 4 + j;
            if (gr < N) {
#pragma unroll
                for (int nt = 0; nt < NT; nt++) {
                    float v = acc[mt][nt][j];
                    C[(size_t)gr * NCOLS + n0 + nt * 16 + l15] = v;
                    C16[(size_t)gr * NCOLS + n0 + nt * 16 + l15] = f2h(v);
                }
            }
        }
    }
}

// ---------------------------------------------------------------------------
// attention dot products
// ---------------------------------------------------------------------------
__global__ void attdot1(const float* __restrict__ h, const float* __restrict__ asrc,
                        const float* __restrict__ adst, float* __restrict__ as,
                        float* __restrict__ ad, int N) {
    int t = threadIdx.x;
    int node = blockIdx.x * 2 + (t >> 7);
    int j = t & 127;
    if (node >= N) return;
    float v = h[(size_t)node * 128 + j];
    float s = v * asrc[j];
    float d = v * adst[j];
#pragma unroll
    for (int o = 1; o < 32; o <<= 1) { s += __shfl_xor(s, o); d += __shfl_xor(d, o); }
    if ((j & 31) == 0) { int head = j >> 5; as[node * 4 + head] = s; ad[node * 4 + head] = d; }
}

__global__ void attdot2(const float* __restrict__ h, const float* __restrict__ asrc,
                        const float* __restrict__ adst, float* __restrict__ as,
                        float* __restrict__ ad, int N) {
    int t = threadIdx.x;
    int node = blockIdx.x * 4 + (t >> 6);
    int j = t & 63;
    if (node >= N) return;
    float v = h[(size_t)node * 64 + j];
    float s = v * asrc[j];
    float d = v * adst[j];
#pragma unroll
    for (int o = 1; o < 64; o <<= 1) { s += __shfl_xor(s, o); d += __shfl_xor(d, o); }
    if (j == 0) { as[node] = s; ad[node] = d; }
}

// ---------------------------------------------------------------------------
// CSR build: histogram -> 2-level exclusive scan -> fill
// ---------------------------------------------------------------------------
__global__ void count_k(const int* __restrict__ dstIdx, int* __restrict__ counts, int E) {
    int e = blockIdx.x * 256 + threadIdx.x;
    if (e < E) atomicAdd(&counts[dstIdx[e]], 1);
}

__global__ void scan_block(const int* __restrict__ in, int* __restrict__ out,
                           int* __restrict__ bsums, int n) {
    __shared__ int lds[256];
    int t = threadIdx.x;
    int base = blockIdx.x * 1024 + t * 4;
    int v0 = 0, v1 = 0, v2 = 0, v3 = 0;
    if (base + 0 < n) v0 = in[base + 0];
    if (base + 1 < n) v1 = in[base + 1];
    if (base + 2 < n) v2 = in[base + 2];
    if (base + 3 < n) v3 = in[base + 3];
    int tsum = v0 + v1 + v2 + v3;
    lds[t] = tsum;
    __syncthreads();
    int val = tsum;
    for (int o = 1; o < 256; o <<= 1) {
        int other = (t >= o) ? lds[t - o] : 0;
        __syncthreads();
        val += other; lds[t] = val;
        __syncthreads();
    }
    if (t == 255) bsums[blockIdx.x] = val;
    int run = val - tsum;
    if (base + 0 < n) out[base + 0] = run; run += v0;
    if (base + 1 < n) out[base + 1] = run; run += v1;
    if (base + 2 < n) out[base + 2] = run; run += v2;
    if (base + 3 < n) out[base + 3] = run;
}

__global__ void scan_sums(int* __restrict__ bsums, int nb) {
    __shared__ int lds[256];
    int t = threadIdx.x;
    int orig = (t < nb) ? bsums[t] : 0;
    lds[t] = orig;
    __syncthreads();
    int val = orig;
    for (int o = 1; o < 256; o <<= 1) {
        int other = (t >= o) ? lds[t - o] : 0;
        __syncthreads();
        val += other; lds[t] = val;
        __syncthreads();
    }
    if (t < nb) bsums[t] = val - orig;
}

__global__ void add_offsets(int* __restrict__ rowptr, const int* __restrict__ bsums,
                            int* __restrict__ cursor, int n, int total) {
    int i = blockIdx.x * 256 + threadIdx.x;
    if (i < n) {
        int v = rowptr[i] + bsums[i >> 10];
        rowptr[i] = v;
        cursor[i] = v;
    } else if (i == n) {
        rowptr[n] = total;
    }
}

__global__ void fill_k(const int* __restrict__ srcIdx, const int* __restrict__ dstIdx,
                       int* __restrict__ cursor, int* __restrict__ esrc, int E) {
    int e = blockIdx.x * 256 + threadIdx.x;
    if (e < E) {
        int pos = atomicAdd(&cursor[dstIdx[e]], 1);
        esrc[pos] = srcIdx[e];
    }
}

// ---------------------------------------------------------------------------
// Layer-1 aggregation. One wave per dst node. Phase B: lane-parallel edge
// weights (m=0) -> ew[e][4] + f32 denominator. Phase C: fp16 gather,
// 16 lanes x 16B = one 256B row, 4 edges/iter; f32 accumulate.
// ---------------------------------------------------------------------------
__launch_bounds__(256)
__global__ void aggregate1(const float* __restrict__ h1, const ushort* __restrict__ h16,
                           const float* __restrict__ as1, const float* __restrict__ ad1,
                           const int* __restrict__ rowptr, const int* __restrict__ esrc,
                           float* __restrict__ ew, const float* __restrict__ b1,
                           float* __restrict__ out1, int N) {
    int wid = threadIdx.x >> 6, lane = threadIdx.x & 63;
    int node = blockIdx.x * 4 + wid;
    if (node >= N) return;
    float4 asn = *(const float4*)&as1[node * 4];
    float4 adn = *(const float4*)&ad1[node * 4];
    float4 selfw = exp4(leaky4(add4(asn, adn)));
    int start = rowptr[node], end = rowptr[node + 1];

    // phase B: per-edge weights + denominator
    float4 ssum = make_float4(0.f, 0.f, 0.f, 0.f);
    for (int e = start + lane; e < end; e += 64) {
        int s = esrc[e];
        float4 w = exp4(leaky4(add4(*(const float4*)&as1[s * 4], adn)));
        *(float4*)&ew[(size_t)e * 4] = w;
        ssum = add4(ssum, w);
    }
#pragma unroll
    for (int o = 1; o < 64; o <<= 1) {
        ssum.x += __shfl_xor(ssum.x, o);
        ssum.y += __shfl_xor(ssum.y, o);
        ssum.z += __shfl_xor(ssum.z, o);
        ssum.w += __shfl_xor(ssum.w, o);
    }
    float4 denom = add4(ssum, selfw);

    int q = lane >> 4, c = lane & 15;   // group q handles edge e+q; ch 8c..8c+7
    int hh = c >> 2;                    // head of this lane's 8 channels
    float inv = 1.f / (pick4(denom, hh) + 1e-16f);
    float sw = pick4(selfw, hh);

    // phase C: fp16 gather-FMA, 4 edges per iteration
    float acc[8] = {0.f, 0.f, 0.f, 0.f, 0.f, 0.f, 0.f, 0.f};
#pragma unroll 2
    for (int e = start; e < end; e += 4) {
        int em = e + q;
        int s = 0; float w = 0.f;
        if (em < end) { s = esrc[em]; w = ew[(size_t)em * 4 + hh]; }
        half8 hv = *(const half8*)&h16[(size_t)s * 128 + c * 8];
#pragma unroll
        for (int j = 0; j < 8; j++) acc[j] += w * (float)hv[j];
    }
#pragma unroll
    for (int j = 0; j < 8; j++) {
        acc[j] += __shfl_xor(acc[j], 16);
        acc[j] += __shfl_xor(acc[j], 32);
    }
    if (q == 0) {
        const float* hp = &h1[(size_t)node * 128 + c * 8];
        const float* bb = &b1[c * 8];
        float o[8];
#pragma unroll
        for (int j = 0; j < 8; j++)
            o[j] = fmaxf((acc[j] + sw * hp[j]) * inv + bb[j], 0.f);
        float4* op = (float4*)&out1[(size_t)node * 128 + c * 8];
        op[0] = make_float4(o[0], o[1], o[2], o[3]);
        op[1] = make_float4(o[4], o[5], o[6], o[7]);
    }
}

// ---------------------------------------------------------------------------
// Layer-2 aggregation (H=1, C=64): fp16 gather, 8 lanes x 16B = one 128B row,
// 8 edges/iter.
// ---------------------------------------------------------------------------
__launch_bounds__(256)
__global__ void aggregate2(const float* __restrict__ h2, const ushort* __restrict__ h16,
                           const float* __restrict__ as2, const float* __restrict__ ad2,
                           const int* __restrict__ rowptr, const int* __restrict__ esrc,
                           float* __restrict__ ew, const float* __restrict__ b2,
                           float* __restrict__ out, int N) {
    int wid = threadIdx.x >> 6, lane = threadIdx.x & 63;
    int node = blockIdx.x * 4 + wid;
    if (node >= N) return;
    float adn = ad2[node];
    float selfw = __expf(leakys(as2[node] + adn));
    int start = rowptr[node], end = rowptr[node + 1];

    float ssum = 0.f;
    for (int e = start + lane; e < end; e += 64) {
        int s = esrc[e];
        float w = __expf(leakys(as2[s] + adn));
        ew[e] = w;
        ssum += w;
    }
#pragma unroll
    for (int o = 1; o < 64; o <<= 1) ssum += __shfl_xor(ssum, o);
    float inv = 1.f / (ssum + selfw + 1e-16f);

    int q = lane >> 3, c = lane & 7;    // group q handles edge e+q; ch 8c..8c+7
    float acc[8] = {0.f, 0.f, 0.f, 0.f, 0.f, 0.f, 0.f, 0.f};
#pragma unroll 2
    for (int e = start; e < end; e += 8) {
        int em = e + q;
        int s = 0; float w = 0.f;
        if (em < end) { s = esrc[em]; w = ew[em]; }
        half8 hv = *(const half8*)&h16[(size_t)s * 64 + c * 8];
#pragma unroll
        for (int j = 0; j < 8; j++) acc[j] += w * (float)hv[j];
    }
#pragma unroll
    for (int j = 0; j < 8; j++) {
        acc[j] += __shfl_xor(acc[j], 8);
        acc[j] += __shfl_xor(acc[j], 16);
        acc[j] += __shfl_xor(acc[j], 32);
    }
    if (lane < 8) {
        const float* hp = &h2[(size_t)node * 64 + c * 8];
        const float* bb = &b2[c * 8];
        float o[8];
#pragma unroll
        for (int j = 0; j < 8; j++)
            o[j] = (acc[j] + selfw * hp[j]) * inv + bb[j];
        float4* op = (float4*)&out[(size_t)node * 64 + c * 8];
        op[0] = make_float4(o[0], o[1], o[2], o[3]);
        op[1] = make_float4(o[4], o[5], o[6], o[7]);
    }
}

// ---------------------------------------------------------------------------
extern "C" void kernel_launch(void* const* d_in, const int* in_sizes, int n_in,
                              void* d_out, int out_size, void* d_ws, size_t ws_size,
                              hipStream_t stream) {
    const float* x      = (const float*)d_in[0];
    const int*   ei     = (const int*)d_in[1];
    const float* W1     = (const float*)d_in[2];
    const float* att_s1 = (const float*)d_in[3];
    const float* att_d1 = (const float*)d_in[4];
    const float* b1     = (const float*)d_in[5];
    const float* W2     = (const float*)d_in[6];
    const float* att_s2 = (const float*)d_in[7];
    const float* att_d2 = (const float*)d_in[8];
    const float* b2     = (const float*)d_in[9];

    const int N = in_sizes[0] / 128;
    const int E = in_sizes[1] / 2;

    char* ws = (char*)d_ws;
    size_t off = 0;
    auto alloc = [&](size_t bytes) -> void* {
        off = (off + 255) & ~(size_t)255;
        void* p = ws + off;
        off += bytes;
        return p;
    };
    float* h1     = (float*)alloc((size_t)N * 128 * 4);
    float* out1   = (float*)alloc((size_t)N * 128 * 4);
    ushort* h16   = (ushort*)alloc((size_t)N * 128 * 2);  // fp16 rows (L1; reused L2)
    float* as1    = (float*)alloc((size_t)N * 4 * 4);
    float* ad1    = (float*)alloc((size_t)N * 4 * 4);
    int*   rowptr = (int*)alloc((size_t)(N + 1) * 4);
    int*   counts = (int*)alloc((size_t)N * 4);
    int*   cursor = (int*)alloc((size_t)N * 4);
    const int nb = (N + 1023) / 1024;
    int*   bsums  = (int*)alloc((size_t)nb * 4);
    int*   esrc   = (int*)alloc((size_t)E * 4);
    float* ew1    = (float*)alloc((size_t)E * 4 * 4);
    ushort* Wt1h  = (ushort*)alloc(128 * 128 * 2);
    ushort* Wt1l  = (ushort*)alloc(128 * 128 * 2);
    ushort* Wt2h  = (ushort*)alloc(64 * 128 * 2);
    ushort* Wt2l  = (ushort*)alloc(64 * 128 * 2);
    float* h2   = h1;                                  // h1 dead after aggregate1
    float* as2  = (float*)((char*)h1 + (size_t)N * 64 * 4);
    float* ad2  = as2 + N;
    ushort* h16b = h16;                                // fp16 rows for layer 2
    float* ew2  = ew1;                                 // ew1 dead after aggregate1

    const int* srcIdx = ei;
    const int* dstIdx = ei + E;

    hipMemsetAsync(counts, 0, (size_t)N * 4, stream);

    prep_w<<<64, 256, 0, stream>>>(W1, Wt1h, Wt1l, 128);
    prep_w<<<32, 256, 0, stream>>>(W2, Wt2h, Wt2l, 64);

    gemm_mfma<128><<<(N + 63) / 64, 256, 0, stream>>>(x, Wt1h, Wt1l, h1, h16, N);
    attdot1<<<(N + 1) / 2, 256, 0, stream>>>(h1, att_s1, att_d1, as1, ad1, N);

    count_k<<<(E + 255) / 256, 256, 0, stream>>>(dstIdx, counts, E);
    scan_block<<<nb, 256, 0, stream>>>(counts, rowptr, bsums, N);
    scan_sums<<<1, 256, 0, stream>>>(bsums, nb);
    add_offsets<<<(N + 1 + 255) / 256, 256, 0, stream>>>(rowptr, bsums, cursor, N, E);
    fill_k<<<(E + 255) / 256, 256, 0, stream>>>(srcIdx, dstIdx, cursor, esrc, E);

    aggregate1<<<(N + 3) / 4, 256, 0, stream>>>(h1, h16, as1, ad1, rowptr, esrc, ew1,
                                                b1, out1, N);

    gemm_mfma<64><<<(N + 63) / 64, 256, 0, stream>>>(out1, Wt2h, Wt2l, h2, h16b, N);
    attdot2<<<(N + 3) / 4, 256, 0, stream>>>(h2, att_s2, att_d2, as2, ad2, N);

    aggregate2<<<(N + 3) / 4, 256, 0, stream>>>(h2, h16b, as2, ad2, rowptr, esrc, ew2,
                                                b2, (float*)d_out, N);
}

// Round 5
// 336.983 us; speedup vs baseline: 3.0408x; 1.3658x over previous
//
#include <hip/hip_runtime.h>
#include <hip/hip_bf16.h>

#define DEV static __device__ __forceinline__

typedef __attribute__((ext_vector_type(4))) float f32x4;
typedef __attribute__((ext_vector_type(8))) short bf16x8;
typedef __attribute__((ext_vector_type(8))) _Float16 half8;

DEV float leakys(float v) { return v > 0.f ? v : 0.2f * v; }
DEV float4 add4(float4 a, float4 b) { return make_float4(a.x+b.x, a.y+b.y, a.z+b.z, a.w+b.w); }
DEV float4 leaky4(float4 v) { return make_float4(leakys(v.x), leakys(v.y), leakys(v.z), leakys(v.w)); }
DEV float4 exp4(float4 v) { return make_float4(__expf(v.x), __expf(v.y), __expf(v.z), __expf(v.w)); }
DEV float pick4(float4 v, int i) {
    float r = v.x;
    r = (i == 1) ? v.y : r;
    r = (i == 2) ? v.z : r;
    r = (i == 3) ? v.w : r;
    return r;
}

DEV ushort f2bf(float f) {
    union { float f; unsigned u; } v; v.f = f;
    unsigned u = v.u;
    unsigned r = (u + 0x7FFFu + ((u >> 16) & 1u)) >> 16;   // RNE
    return (ushort)r;
}
DEV float bf2f(ushort h) {
    union { unsigned u; float f; } v; v.u = ((unsigned)h) << 16;
    return v.f;
}
DEV ushort f2h(float f) {
    union { _Float16 h; ushort u; } v;
    v.h = (_Float16)f;
    return v.u;
}

// ---------------------------------------------------------------------------
// One-time W prep: W[K=128][NC] f32 -> transposed bf16 hi/lo  Wt[n][k].
// ---------------------------------------------------------------------------
__global__ void prep_w(const float* __restrict__ W, ushort* __restrict__ Wth,
                       ushort* __restrict__ Wtl, int NC) {
    int i = blockIdx.x * 256 + threadIdx.x;
    if (i >= 128 * NC) return;
    int k = i / NC, n = i % NC;
    float v = W[i];
    ushort hi = f2bf(v);
    ushort lo = f2bf(v - bf2f(hi));
    Wth[n * 128 + k] = hi;
    Wtl[n * 128 + k] = lo;
}

// ---------------------------------------------------------------------------
// MFMA GEMM: C[N][NCOLS] = A[N][128] @ W[128][NCOLS], split-bf16 (3 MFMA).
// Epilogue also writes an fp16 copy (C16) used by the gather kernels.
// ---------------------------------------------------------------------------
template <int NCOLS>
__launch_bounds__(256, 2)
__global__ void gemm_mfma(const float* __restrict__ A, const ushort* __restrict__ Wth,
                          const ushort* __restrict__ Wtl, float* __restrict__ C,
                          ushort* __restrict__ C16, int N) {
    constexpr int NT = NCOLS / 64;          // 16-wide n-tiles per wave
    __shared__ ushort Xhi[64 * 128];
    __shared__ ushort Xlo[64 * 128];
    const int t = threadIdx.x;
    const int wv = t >> 6, l = t & 63;
    const int l15 = l & 15, lhi = l >> 4;
    const int row0 = blockIdx.x * 64;
    const int n0 = wv * 16 * NT;

    for (int i = t; i < 2048; i += 256) {
        int r = i >> 5, c4 = i & 31;
        int gr = row0 + r;
        float4 v = make_float4(0.f, 0.f, 0.f, 0.f);
        if (gr < N) v = ((const float4*)A)[(size_t)gr * 32 + c4];
        ushort4 hi, lo;
        hi.x = f2bf(v.x); lo.x = f2bf(v.x - bf2f(hi.x));
        hi.y = f2bf(v.y); lo.y = f2bf(v.y - bf2f(hi.y));
        hi.z = f2bf(v.z); lo.z = f2bf(v.z - bf2f(hi.z));
        hi.w = f2bf(v.w); lo.w = f2bf(v.w - bf2f(hi.w));
        int idx = (r * 128 + c4 * 4) ^ ((r & 7) << 3);
        *(ushort4*)&Xhi[idx] = hi;
        *(ushort4*)&Xlo[idx] = lo;
    }
    __syncthreads();

    f32x4 acc[4][NT];
#pragma unroll
    for (int mt = 0; mt < 4; mt++)
#pragma unroll
        for (int nt = 0; nt < NT; nt++) acc[mt][nt] = (f32x4){0.f, 0.f, 0.f, 0.f};

#pragma unroll
    for (int ks = 0; ks < 4; ks++) {
        bf16x8 ah[4], al[4];
#pragma unroll
        for (int mt = 0; mt < 4; mt++) {
            int row = mt * 16 + l15;
            int idx = (row * 128 + ks * 32 + lhi * 8) ^ ((row & 7) << 3);
            ah[mt] = *(const bf16x8*)&Xhi[idx];
            al[mt] = *(const bf16x8*)&Xlo[idx];
        }
#pragma unroll
        for (int nt = 0; nt < NT; nt++) {
            size_t wo = (size_t)(n0 + nt * 16 + l15) * 128 + ks * 32 + lhi * 8;
            bf16x8 bh = *(const bf16x8*)&Wth[wo];
            bf16x8 bl = *(const bf16x8*)&Wtl[wo];
#pragma unroll
            for (int mt = 0; mt < 4; mt++) {
                acc[mt][nt] = __builtin_amdgcn_mfma_f32_16x16x32_bf16(ah[mt], bh, acc[mt][nt], 0, 0, 0);
                acc[mt][nt] = __builtin_amdgcn_mfma_f32_16x16x32_bf16(ah[mt], bl, acc[mt][nt], 0, 0, 0);
                acc[mt][nt] = __builtin_amdgcn_mfma_f32_16x16x32_bf16(al[mt], bh, acc[mt][nt], 0, 0, 0);
            }
        }
    }
#pragma unroll
    for (int mt = 0; mt < 4; mt++) {
#pragma unroll
        for (int j = 0; j < 4; j++) {
            int gr = row0 + mt * 16 + lhi * 4 + j;
            if (gr < N) {
#pragma unroll
                for (int nt = 0; nt < NT; nt++) {
                    float v = acc[mt][nt][j];
                    C[(size_t)gr * NCOLS + n0 + nt * 16 + l15] = v;
                    C16[(size_t)gr * NCOLS + n0 + nt * 16 + l15] = f2h(v);
                }
            }
        }
    }
}

// ---------------------------------------------------------------------------
// attention dot products
// ---------------------------------------------------------------------------
__global__ void attdot1(const float* __restrict__ h, const float* __restrict__ asrc,
                        const float* __restrict__ adst, float* __restrict__ as,
                        float* __restrict__ ad, int N) {
    int t = threadIdx.x;
    int node = blockIdx.x * 2 + (t >> 7);
    int j = t & 127;
    if (node >= N) return;
    float v = h[(size_t)node * 128 + j];
    float s = v * asrc[j];
    float d = v * adst[j];
#pragma unroll
    for (int o = 1; o < 32; o <<= 1) { s += __shfl_xor(s, o); d += __shfl_xor(d, o); }
    if ((j & 31) == 0) { int head = j >> 5; as[node * 4 + head] = s; ad[node * 4 + head] = d; }
}

__global__ void attdot2(const float* __restrict__ h, const float* __restrict__ asrc,
                        const float* __restrict__ adst, float* __restrict__ as,
                        float* __restrict__ ad, int N) {
    int t = threadIdx.x;
    int node = blockIdx.x * 4 + (t >> 6);
    int j = t & 63;
    if (node >= N) return;
    float v = h[(size_t)node * 64 + j];
    float s = v * asrc[j];
    float d = v * adst[j];
#pragma unroll
    for (int o = 1; o < 64; o <<= 1) { s += __shfl_xor(s, o); d += __shfl_xor(d, o); }
    if (j == 0) { as[node] = s; ad[node] = d; }
}

// ---------------------------------------------------------------------------
// CSR build, bucket counting sort. Bucket = 512 consecutive dst nodes
// (NB = ceil(N/512) <= 256). All scatters land in L2-resident windows.
// ---------------------------------------------------------------------------
__global__ void bcount(const int* __restrict__ dstIdx, int* __restrict__ bcounts, int E) {
    __shared__ int hist[256];
    int t = threadIdx.x;
    hist[t] = 0;
    __syncthreads();
    for (int e = blockIdx.x * 256 + t; e < E; e += gridDim.x * 256)
        atomicAdd(&hist[dstIdx[e] >> 9], 1);
    __syncthreads();
    int h = hist[t];
    if (h) atomicAdd(&bcounts[t], h);
}

__global__ void bscan(const int* __restrict__ bcounts, int* __restrict__ bbase,
                      int* __restrict__ bcursor, int NB) {
    __shared__ int lds[256];
    int t = threadIdx.x;
    int v = (t < NB) ? bcounts[t] : 0;
    lds[t] = v;
    __syncthreads();
    int val = v;
    for (int o = 1; o < 256; o <<= 1) {
        int other = (t >= o) ? lds[t - o] : 0;
        __syncthreads();
        val += other; lds[t] = val;
        __syncthreads();
    }
    if (t < NB) { bbase[t] = val - v; bcursor[t] = val - v; }
}

// per-block multisplit: one ranged atomic per (block,bucket), short coalesced runs
__global__ void bscatter(const int* __restrict__ srcIdx, const int* __restrict__ dstIdx,
                         int* __restrict__ bcursor, uint2* __restrict__ ebuf, int E) {
    __shared__ int hist[256];
    __shared__ int gofs[256];
    int t = threadIdx.x;
    hist[t] = 0;
    __syncthreads();
    int e0 = blockIdx.x * 4096;
    int e1 = min(E, e0 + 4096);
    for (int e = e0 + t; e < e1; e += 256)
        atomicAdd(&hist[dstIdx[e] >> 9], 1);
    __syncthreads();
    int h = hist[t];
    if (h) gofs[t] = atomicAdd(&bcursor[t], h);
    __syncthreads();
    hist[t] = 0;
    __syncthreads();
    for (int e = e0 + t; e < e1; e += 256) {
        int d = dstIdx[e];
        int b = d >> 9;
        int r = atomicAdd(&hist[b], 1);
        uint2 v; v.x = (unsigned)srcIdx[e]; v.y = (unsigned)d;
        ebuf[gofs[b] + r] = v;
    }
}

// one block per bucket: LDS node-histogram -> LDS scan -> rowptr + local fill
__global__ void bfill(const uint2* __restrict__ ebuf, const int* __restrict__ bbase,
                      int* __restrict__ rowptr, int* __restrict__ esrc,
                      int N, int NB, int E) {
    __shared__ int cnt[512];
    __shared__ int lds[256];
    int b = blockIdx.x, t = threadIdx.x;
    int n0 = b << 9;
    cnt[t] = 0; cnt[t + 256] = 0;
    __syncthreads();
    int e0 = bbase[b];
    int e1 = (b + 1 < NB) ? bbase[b + 1] : E;
    for (int e = e0 + t; e < e1; e += 256)
        atomicAdd(&cnt[ebuf[e].y & 511], 1);
    __syncthreads();
    int c0 = cnt[2 * t], c1 = cnt[2 * t + 1];
    int s = c0 + c1;
    lds[t] = s;
    __syncthreads();
    int val = s;
    for (int o = 1; o < 256; o <<= 1) {
        int other = (t >= o) ? lds[t - o] : 0;
        __syncthreads();
        val += other; lds[t] = val;
        __syncthreads();
    }
    int p = val - s;           // exclusive prefix of this thread's pair
    int nrem = N - n0;
    if (2 * t < nrem)     rowptr[n0 + 2 * t]     = e0 + p;
    if (2 * t + 1 < nrem) rowptr[n0 + 2 * t + 1] = e0 + p + c0;
    cnt[2 * t] = p; cnt[2 * t + 1] = p + c0;   // local cursors
    __syncthreads();
    for (int e = e0 + t; e < e1; e += 256) {
        uint2 ed = ebuf[e];
        int r = atomicAdd(&cnt[ed.y & 511], 1);
        esrc[e0 + r] = (int)ed.x;
    }
    if (b == 0 && t == 0) rowptr[N] = E;
}

// ---------------------------------------------------------------------------
// Layer-1 aggregation. Phase B: lane-parallel edge weights (m=0), f32
// denominator only (weights recomputed in phase C from L2-resident as1).
// Phase C: fp16 gather, 16 lanes x 16B = one 256B row, 4 edges/iter.
// ---------------------------------------------------------------------------
__launch_bounds__(256)
__global__ void aggregate1(const float* __restrict__ h1, const ushort* __restrict__ h16,
                           const float* __restrict__ as1, const float* __restrict__ ad1,
                           const int* __restrict__ rowptr, const int* __restrict__ esrc,
                           const float* __restrict__ b1, float* __restrict__ out1, int N) {
    int wid = threadIdx.x >> 6, lane = threadIdx.x & 63;
    int node = blockIdx.x * 4 + wid;
    if (node >= N) return;
    float4 asn = *(const float4*)&as1[node * 4];
    float4 adn = *(const float4*)&ad1[node * 4];
    float4 selfw = exp4(leaky4(add4(asn, adn)));
    int start = rowptr[node], end = rowptr[node + 1];

    // phase B: denominator
    float4 ssum = make_float4(0.f, 0.f, 0.f, 0.f);
    for (int e = start + lane; e < end; e += 64) {
        int s = esrc[e];
        ssum = add4(ssum, exp4(leaky4(add4(*(const float4*)&as1[s * 4], adn))));
    }
#pragma unroll
    for (int o = 1; o < 64; o <<= 1) {
        ssum.x += __shfl_xor(ssum.x, o);
        ssum.y += __shfl_xor(ssum.y, o);
        ssum.z += __shfl_xor(ssum.z, o);
        ssum.w += __shfl_xor(ssum.w, o);
    }
    float4 denom = add4(ssum, selfw);

    int q = lane >> 4, c = lane & 15;   // group q handles edge e+q; ch 8c..8c+7
    int hh = c >> 2;                    // head of this lane's 8 channels
    float inv = 1.f / (pick4(denom, hh) + 1e-16f);
    float sw = pick4(selfw, hh);
    float adh = pick4(adn, hh);

    // phase C: fp16 gather-FMA, 4 edges per iteration; w recomputed (as1 L2-hot)
    float acc[8] = {0.f, 0.f, 0.f, 0.f, 0.f, 0.f, 0.f, 0.f};
#pragma unroll 2
    for (int e = start; e < end; e += 4) {
        int em = e + q;
        int s = 0; float w = 0.f;
        if (em < end) { s = esrc[em]; w = __expf(leakys(as1[s * 4 + hh] + adh)); }
        half8 hv = *(const half8*)&h16[(size_t)s * 128 + c * 8];
#pragma unroll
        for (int j = 0; j < 8; j++) acc[j] += w * (float)hv[j];
    }
#pragma unroll
    for (int j = 0; j < 8; j++) {
        acc[j] += __shfl_xor(acc[j], 16);
        acc[j] += __shfl_xor(acc[j], 32);
    }
    if (q == 0) {
        const float* hp = &h1[(size_t)node * 128 + c * 8];
        const float* bb = &b1[c * 8];
        float o[8];
#pragma unroll
        for (int j = 0; j < 8; j++)
            o[j] = fmaxf((acc[j] + sw * hp[j]) * inv + bb[j], 0.f);
        float4* op = (float4*)&out1[(size_t)node * 128 + c * 8];
        op[0] = make_float4(o[0], o[1], o[2], o[3]);
        op[1] = make_float4(o[4], o[5], o[6], o[7]);
    }
}

// ---------------------------------------------------------------------------
// Layer-2 aggregation (H=1, C=64): fp16 gather, 8 lanes x 16B = one 128B row,
// 8 edges/iter; w recomputed from L2-resident as2.
// ---------------------------------------------------------------------------
__launch_bounds__(256)
__global__ void aggregate2(const float* __restrict__ h2, const ushort* __restrict__ h16,
                           const float* __restrict__ as2, const float* __restrict__ ad2,
                           const int* __restrict__ rowptr, const int* __restrict__ esrc,
                           const float* __restrict__ b2, float* __restrict__ out, int N) {
    int wid = threadIdx.x >> 6, lane = threadIdx.x & 63;
    int node = blockIdx.x * 4 + wid;
    if (node >= N) return;
    float adn = ad2[node];
    float selfw = __expf(leakys(as2[node] + adn));
    int start = rowptr[node], end = rowptr[node + 1];

    float ssum = 0.f;
    for (int e = start + lane; e < end; e += 64)
        ssum += __expf(leakys(as2[esrc[e]] + adn));
#pragma unroll
    for (int o = 1; o < 64; o <<= 1) ssum += __shfl_xor(ssum, o);
    float inv = 1.f / (ssum + selfw + 1e-16f);

    int q = lane >> 3, c = lane & 7;    // group q handles edge e+q; ch 8c..8c+7
    float acc[8] = {0.f, 0.f, 0.f, 0.f, 0.f, 0.f, 0.f, 0.f};
#pragma unroll 2
    for (int e = start; e < end; e += 8) {
        int em = e + q;
        int s = 0; float w = 0.f;
        if (em < end) { s = esrc[em]; w = __expf(leakys(as2[s] + adn)); }
        half8 hv = *(const half8*)&h16[(size_t)s * 64 + c * 8];
#pragma unroll
        for (int j = 0; j < 8; j++) acc[j] += w * (float)hv[j];
    }
#pragma unroll
    for (int j = 0; j < 8; j++) {
        acc[j] += __shfl_xor(acc[j], 8);
        acc[j] += __shfl_xor(acc[j], 16);
        acc[j] += __shfl_xor(acc[j], 32);
    }
    if (lane < 8) {
        const float* hp = &h2[(size_t)node * 64 + c * 8];
        const float* bb = &b2[c * 8];
        float o[8];
#pragma unroll
        for (int j = 0; j < 8; j++)
            o[j] = (acc[j] + selfw * hp[j]) * inv + bb[j];
        float4* op = (float4*)&out[(size_t)node * 64 + c * 8];
        op[0] = make_float4(o[0], o[1], o[2], o[3]);
        op[1] = make_float4(o[4], o[5], o[6], o[7]);
    }
}

// ---------------------------------------------------------------------------
extern "C" void kernel_launch(void* const* d_in, const int* in_sizes, int n_in,
                              void* d_out, int out_size, void* d_ws, size_t ws_size,
                              hipStream_t stream) {
    const float* x      = (const float*)d_in[0];
    const int*   ei     = (const int*)d_in[1];
    const float* W1     = (const float*)d_in[2];
    const float* att_s1 = (const float*)d_in[3];
    const float* att_d1 = (const float*)d_in[4];
    const float* b1     = (const float*)d_in[5];
    const float* W2     = (const float*)d_in[6];
    const float* att_s2 = (const float*)d_in[7];
    const float* att_d2 = (const float*)d_in[8];
    const float* b2     = (const float*)d_in[9];

    const int N = in_sizes[0] / 128;
    const int E = in_sizes[1] / 2;
    const int NB = (N + 511) >> 9;         // buckets of 512 dst nodes (<=256)

    char* ws = (char*)d_ws;
    size_t off = 0;
    auto alloc = [&](size_t bytes) -> void* {
        off = (off + 255) & ~(size_t)255;
        void* p = ws + off;
        off += bytes;
        return p;
    };
    float* h1     = (float*)alloc((size_t)N * 128 * 4);
    float* out1   = (float*)alloc((size_t)N * 128 * 4);
    ushort* h16   = (ushort*)alloc((size_t)N * 128 * 2);
    float* as1    = (float*)alloc((size_t)N * 4 * 4);
    float* ad1    = (float*)alloc((size_t)N * 4 * 4);
    int*   rowptr = (int*)alloc((size_t)(N + 1) * 4);
    int*   esrc   = (int*)alloc((size_t)E * 4);
    int*   bcounts = (int*)alloc(256 * 4);
    int*   bbase   = (int*)alloc(256 * 4);
    int*   bcursor = (int*)alloc(256 * 4);
    ushort* Wt1h  = (ushort*)alloc(128 * 128 * 2);
    ushort* Wt1l  = (ushort*)alloc(128 * 128 * 2);
    ushort* Wt2h  = (ushort*)alloc(64 * 128 * 2);
    ushort* Wt2l  = (ushort*)alloc(64 * 128 * 2);
    float* h2   = h1;                                  // h1 dead after aggregate1
    float* as2  = (float*)((char*)h1 + (size_t)N * 64 * 4);
    float* ad2  = as2 + N;
    ushort* h16b = h16;
    uint2* ebuf = (uint2*)out1;   // E*8 <= N*512 bytes; dead before aggregate1 writes out1

    const int* srcIdx = ei;
    const int* dstIdx = ei + E;

    hipMemsetAsync(bcounts, 0, 256 * 4, stream);

    prep_w<<<64, 256, 0, stream>>>(W1, Wt1h, Wt1l, 128);
    prep_w<<<32, 256, 0, stream>>>(W2, Wt2h, Wt2l, 64);

    gemm_mfma<128><<<(N + 63) / 64, 256, 0, stream>>>(x, Wt1h, Wt1l, h1, h16, N);
    attdot1<<<(N + 1) / 2, 256, 0, stream>>>(h1, att_s1, att_d1, as1, ad1, N);

    bcount<<<1024, 256, 0, stream>>>(dstIdx, bcounts, E);
    bscan<<<1, 256, 0, stream>>>(bcounts, bbase, bcursor, NB);
    bscatter<<<(E + 4095) / 4096, 256, 0, stream>>>(srcIdx, dstIdx, bcursor, ebuf, E);
    bfill<<<NB, 256, 0, stream>>>(ebuf, bbase, rowptr, esrc, N, NB, E);

    aggregate1<<<(N + 3) / 4, 256, 0, stream>>>(h1, h16, as1, ad1, rowptr, esrc,
                                                b1, out1, N);

    gemm_mfma<64><<<(N + 63) / 64, 256, 0, stream>>>(out1, Wt2h, Wt2l, h2, h16b, N);
    attdot2<<<(N + 3) / 4, 256, 0, stream>>>(h2, att_s2, att_d2, as2, ad2, N);

    aggregate2<<<(N + 3) / 4, 256, 0, stream>>>(h2, h16b, as2, ad2, rowptr, esrc,
                                                b2, (float*)d_out, N);
}

// Round 6
// 285.640 us; speedup vs baseline: 3.5873x; 1.1797x over previous
//
#include <hip/hip_runtime.h>
#include <hip/hip_bf16.h>

#define DEV static __device__ __forceinline__

typedef __attribute__((ext_vector_type(4))) float f32x4;
typedef __attribute__((ext_vector_type(8))) short bf16x8;
typedef __attribute__((ext_vector_type(8))) _Float16 half8;

DEV float leakys(float v) { return v > 0.f ? v : 0.2f * v; }
DEV float4 add4(float4 a, float4 b) { return make_float4(a.x+b.x, a.y+b.y, a.z+b.z, a.w+b.w); }
DEV float4 leaky4(float4 v) { return make_float4(leakys(v.x), leakys(v.y), leakys(v.z), leakys(v.w)); }
DEV float4 exp4(float4 v) { return make_float4(__expf(v.x), __expf(v.y), __expf(v.z), __expf(v.w)); }
DEV float pick4(float4 v, int i) {
    float r = v.x;
    r = (i == 1) ? v.y : r;
    r = (i == 2) ? v.z : r;
    r = (i == 3) ? v.w : r;
    return r;
}

DEV ushort f2bf(float f) {
    union { float f; unsigned u; } v; v.f = f;
    unsigned u = v.u;
    unsigned r = (u + 0x7FFFu + ((u >> 16) & 1u)) >> 16;   // RNE
    return (ushort)r;
}
DEV float bf2f(ushort h) {
    union { unsigned u; float f; } v; v.u = ((unsigned)h) << 16;
    return v.f;
}
DEV ushort f2h(float f) {
    union { _Float16 h; ushort u; } v;
    v.h = (_Float16)f;
    return v.u;
}

// ---------------------------------------------------------------------------
// One-time W prep: W[K=128][NC] f32 -> transposed bf16 hi/lo  Wt[n][k].
// ---------------------------------------------------------------------------
__global__ void prep_w(const float* __restrict__ W, ushort* __restrict__ Wth,
                       ushort* __restrict__ Wtl, int NC) {
    int i = blockIdx.x * 256 + threadIdx.x;
    if (i >= 128 * NC) return;
    int k = i / NC, n = i % NC;
    float v = W[i];
    ushort hi = f2bf(v);
    ushort lo = f2bf(v - bf2f(hi));
    Wth[n * 128 + k] = hi;
    Wtl[n * 128 + k] = lo;
}

// ---------------------------------------------------------------------------
// MFMA GEMM: C[N][NCOLS] = A[N][128] @ W[128][NCOLS], split-bf16 (3 MFMA).
// Epilogue writes fp16 copy (C16). For NCOLS==128 it also fuses the
// attention dot-products: wave wv owns cols [32wv,32wv+32) == head wv, so
// a_s/a_d for head wv reduce entirely in-wave from live accumulators.
// ---------------------------------------------------------------------------
template <int NCOLS>
__launch_bounds__(256, 2)
__global__ void gemm_mfma(const float* __restrict__ A, const ushort* __restrict__ Wth,
                          const ushort* __restrict__ Wtl, float* __restrict__ C,
                          ushort* __restrict__ C16,
                          const float* __restrict__ att_s, const float* __restrict__ att_d,
                          float* __restrict__ as_out, float* __restrict__ ad_out, int N) {
    constexpr int NT = NCOLS / 64;          // 16-wide n-tiles per wave
    __shared__ ushort Xhi[64 * 128];
    __shared__ ushort Xlo[64 * 128];
    const int t = threadIdx.x;
    const int wv = t >> 6, l = t & 63;
    const int l15 = l & 15, lhi = l >> 4;
    const int row0 = blockIdx.x * 64;
    const int n0 = wv * 16 * NT;

    for (int i = t; i < 2048; i += 256) {
        int r = i >> 5, c4 = i & 31;
        int gr = row0 + r;
        float4 v = make_float4(0.f, 0.f, 0.f, 0.f);
        if (gr < N) v = ((const float4*)A)[(size_t)gr * 32 + c4];
        ushort4 hi, lo;
        hi.x = f2bf(v.x); lo.x = f2bf(v.x - bf2f(hi.x));
        hi.y = f2bf(v.y); lo.y = f2bf(v.y - bf2f(hi.y));
        hi.z = f2bf(v.z); lo.z = f2bf(v.z - bf2f(hi.z));
        hi.w = f2bf(v.w); lo.w = f2bf(v.w - bf2f(hi.w));
        int idx = (r * 128 + c4 * 4) ^ ((r & 7) << 3);
        *(ushort4*)&Xhi[idx] = hi;
        *(ushort4*)&Xlo[idx] = lo;
    }
    __syncthreads();

    f32x4 acc[4][NT];
#pragma unroll
    for (int mt = 0; mt < 4; mt++)
#pragma unroll
        for (int nt = 0; nt < NT; nt++) acc[mt][nt] = (f32x4){0.f, 0.f, 0.f, 0.f};

#pragma unroll
    for (int ks = 0; ks < 4; ks++) {
        bf16x8 ah[4], al[4];
#pragma unroll
        for (int mt = 0; mt < 4; mt++) {
            int row = mt * 16 + l15;
            int idx = (row * 128 + ks * 32 + lhi * 8) ^ ((row & 7) << 3);
            ah[mt] = *(const bf16x8*)&Xhi[idx];
            al[mt] = *(const bf16x8*)&Xlo[idx];
        }
#pragma unroll
        for (int nt = 0; nt < NT; nt++) {
            size_t wo = (size_t)(n0 + nt * 16 + l15) * 128 + ks * 32 + lhi * 8;
            bf16x8 bh = *(const bf16x8*)&Wth[wo];
            bf16x8 bl = *(const bf16x8*)&Wtl[wo];
#pragma unroll
            for (int mt = 0; mt < 4; mt++) {
                acc[mt][nt] = __builtin_amdgcn_mfma_f32_16x16x32_bf16(ah[mt], bh, acc[mt][nt], 0, 0, 0);
                acc[mt][nt] = __builtin_amdgcn_mfma_f32_16x16x32_bf16(ah[mt], bl, acc[mt][nt], 0, 0, 0);
                acc[mt][nt] = __builtin_amdgcn_mfma_f32_16x16x32_bf16(al[mt], bh, acc[mt][nt], 0, 0, 0);
            }
        }
    }
#pragma unroll
    for (int mt = 0; mt < 4; mt++) {
#pragma unroll
        for (int j = 0; j < 4; j++) {
            int gr = row0 + mt * 16 + lhi * 4 + j;
            if (gr < N) {
#pragma unroll
                for (int nt = 0; nt < NT; nt++) {
                    float v = acc[mt][nt][j];
                    C[(size_t)gr * NCOLS + n0 + nt * 16 + l15] = v;
                    C16[(size_t)gr * NCOLS + n0 + nt * 16 + l15] = f2h(v);
                }
            }
        }
    }
    if constexpr (NT == 2) {
        // fused attdot: head wv = cols [n0, n0+32)
        float as0 = att_s[n0 + l15],      ad0 = att_d[n0 + l15];
        float as1v = att_s[n0 + 16 + l15], ad1v = att_d[n0 + 16 + l15];
#pragma unroll
        for (int mt = 0; mt < 4; mt++) {
#pragma unroll
            for (int j = 0; j < 4; j++) {
                float ps = acc[mt][0][j] * as0 + acc[mt][1][j] * as1v;
                float pd = acc[mt][0][j] * ad0 + acc[mt][1][j] * ad1v;
#pragma unroll
                for (int o = 1; o < 16; o <<= 1) {
                    ps += __shfl_xor(ps, o);
                    pd += __shfl_xor(pd, o);
                }
                if (l15 == 0) {
                    int gr = row0 + mt * 16 + lhi * 4 + j;
                    if (gr < N) {
                        as_out[gr * 4 + wv] = ps;
                        ad_out[gr * 4 + wv] = pd;
                    }
                }
            }
        }
    }
}

// ---------------------------------------------------------------------------
// attention dot products, layer 2 (H=1, C=64)
// ---------------------------------------------------------------------------
__global__ void attdot2(const float* __restrict__ h, const float* __restrict__ asrc,
                        const float* __restrict__ adst, float* __restrict__ as,
                        float* __restrict__ ad, int N) {
    int t = threadIdx.x;
    int node = blockIdx.x * 4 + (t >> 6);
    int j = t & 63;
    if (node >= N) return;
    float v = h[(size_t)node * 64 + j];
    float s = v * asrc[j];
    float d = v * adst[j];
#pragma unroll
    for (int o = 1; o < 64; o <<= 1) { s += __shfl_xor(s, o); d += __shfl_xor(d, o); }
    if (j == 0) { as[node] = s; ad[node] = d; }
}

// ---------------------------------------------------------------------------
// CSR build, bucket counting sort. Bucket = 512 consecutive dst nodes
// (NB = ceil(N/512) <= 256). All scatters land in L2-resident windows.
// ---------------------------------------------------------------------------
__global__ void bcount(const int* __restrict__ dstIdx, int* __restrict__ bcounts, int E) {
    __shared__ int hist[256];
    int t = threadIdx.x;
    hist[t] = 0;
    __syncthreads();
    for (int e = blockIdx.x * 256 + t; e < E; e += gridDim.x * 256)
        atomicAdd(&hist[dstIdx[e] >> 9], 1);
    __syncthreads();
    int h = hist[t];
    if (h) atomicAdd(&bcounts[t], h);
}

__global__ void bscan(const int* __restrict__ bcounts, int* __restrict__ bbase,
                      int* __restrict__ bcursor, int NB) {
    __shared__ int lds[256];
    int t = threadIdx.x;
    int v = (t < NB) ? bcounts[t] : 0;
    lds[t] = v;
    __syncthreads();
    int val = v;
    for (int o = 1; o < 256; o <<= 1) {
        int other = (t >= o) ? lds[t - o] : 0;
        __syncthreads();
        val += other; lds[t] = val;
        __syncthreads();
    }
    if (t < NB) { bbase[t] = val - v; bcursor[t] = val - v; }
}

// per-block multisplit: one ranged atomic per (block,bucket), short coalesced runs
__global__ void bscatter(const int* __restrict__ srcIdx, const int* __restrict__ dstIdx,
                         int* __restrict__ bcursor, uint2* __restrict__ ebuf, int E) {
    __shared__ int hist[256];
    __shared__ int gofs[256];
    int t = threadIdx.x;
    hist[t] = 0;
    __syncthreads();
    int e0 = blockIdx.x * 4096;
    int e1 = min(E, e0 + 4096);
    for (int e = e0 + t; e < e1; e += 256)
        atomicAdd(&hist[dstIdx[e] >> 9], 1);
    __syncthreads();
    int h = hist[t];
    if (h) gofs[t] = atomicAdd(&bcursor[t], h);
    __syncthreads();
    hist[t] = 0;
    __syncthreads();
    for (int e = e0 + t; e < e1; e += 256) {
        int d = dstIdx[e];
        int b = d >> 9;
        int r = atomicAdd(&hist[b], 1);
        uint2 v; v.x = (unsigned)srcIdx[e]; v.y = (unsigned)d;
        ebuf[gofs[b] + r] = v;
    }
}

// one block per bucket: LDS node-histogram -> LDS scan -> rowptr + local fill
__global__ void bfill(const uint2* __restrict__ ebuf, const int* __restrict__ bbase,
                      int* __restrict__ rowptr, int* __restrict__ esrc,
                      int N, int NB, int E) {
    __shared__ int cnt[512];
    __shared__ int lds[256];
    int b = blockIdx.x, t = threadIdx.x;
    int n0 = b << 9;
    cnt[t] = 0; cnt[t + 256] = 0;
    __syncthreads();
    int e0 = bbase[b];
    int e1 = (b + 1 < NB) ? bbase[b + 1] : E;
    for (int e = e0 + t; e < e1; e += 256)
        atomicAdd(&cnt[ebuf[e].y & 511], 1);
    __syncthreads();
    int c0 = cnt[2 * t], c1 = cnt[2 * t + 1];
    int s = c0 + c1;
    lds[t] = s;
    __syncthreads();
    int val = s;
    for (int o = 1; o < 256; o <<= 1) {
        int other = (t >= o) ? lds[t - o] : 0;
        __syncthreads();
        val += other; lds[t] = val;
        __syncthreads();
    }
    int p = val - s;           // exclusive prefix of this thread's pair
    int nrem = N - n0;
    if (2 * t < nrem)     rowptr[n0 + 2 * t]     = e0 + p;
    if (2 * t + 1 < nrem) rowptr[n0 + 2 * t + 1] = e0 + p + c0;
    cnt[2 * t] = p; cnt[2 * t + 1] = p + c0;   // local cursors
    __syncthreads();
    for (int e = e0 + t; e < e1; e += 256) {
        uint2 ed = ebuf[e];
        int r = atomicAdd(&cnt[ed.y & 511], 1);
        esrc[e0 + r] = (int)ed.x;
    }
    if (b == 0 && t == 0) rowptr[N] = E;
}

// ---------------------------------------------------------------------------
// Layer-1 aggregation, single-pass chunked. Per 64-edge chunk: phase 1
// computes each edge's weight ONCE lane-parallel -> per-wave LDS (+denom in
// regs); phase 2 reads {w,s} via LDS broadcast and does the fp16 gather-FMA
// (16 lanes x 16B = one 256B row, 4 edges/iter). Wave-private LDS: no
// barriers (DS ops in-order per wave). m=0 softmax; inv deferred to epilogue.
// ---------------------------------------------------------------------------
__launch_bounds__(256)
__global__ void aggregate1(const float* __restrict__ h1, const ushort* __restrict__ h16,
                           const float* __restrict__ as1, const float* __restrict__ ad1,
                           const int* __restrict__ rowptr, const int* __restrict__ esrc,
                           const float* __restrict__ b1, float* __restrict__ out1, int N) {
    __shared__ float wbuf[4][256];
    __shared__ int   sbuf[4][64];
    int wid = threadIdx.x >> 6, lane = threadIdx.x & 63;
    int node = blockIdx.x * 4 + wid;
    if (node >= N) return;
    float4 asn = *(const float4*)&as1[node * 4];
    float4 adn = *(const float4*)&ad1[node * 4];
    float4 selfw = exp4(leaky4(add4(asn, adn)));
    int start = rowptr[node], end = rowptr[node + 1];

    int q = lane >> 4, c = lane & 15;   // group q handles edge i+q; ch 8c..8c+7
    int hh = c >> 2;                    // head of this lane's 8 channels
    float4 ssum = make_float4(0.f, 0.f, 0.f, 0.f);
    float acc[8] = {0.f, 0.f, 0.f, 0.f, 0.f, 0.f, 0.f, 0.f};

    for (int base = start; base < end; base += 64) {
        int cnt = end - base; if (cnt > 64) cnt = 64;
        // phase 1: per-edge weights (once), denominator partials in regs
        if (lane < cnt) {
            int s = esrc[base + lane];
            float4 w = exp4(leaky4(add4(*(const float4*)&as1[s * 4], adn)));
            sbuf[wid][lane] = s;
            *(float4*)&wbuf[wid][lane * 4] = w;
            ssum = add4(ssum, w);
        }
        // phase 2: fp16 gather-FMA, 4 edges/iter; w,s broadcast from LDS
#pragma unroll 2
        for (int i = 0; i < cnt; i += 4) {
            int ii = i + q;
            int s = 0; float w = 0.f;
            if (ii < cnt) { s = sbuf[wid][ii]; w = wbuf[wid][ii * 4 + hh]; }
            half8 hv = *(const half8*)&h16[(size_t)s * 128 + c * 8];
#pragma unroll
            for (int j = 0; j < 8; j++) acc[j] += w * (float)hv[j];
        }
    }
#pragma unroll
    for (int o = 1; o < 64; o <<= 1) {
        ssum.x += __shfl_xor(ssum.x, o);
        ssum.y += __shfl_xor(ssum.y, o);
        ssum.z += __shfl_xor(ssum.z, o);
        ssum.w += __shfl_xor(ssum.w, o);
    }
    float4 denom = add4(ssum, selfw);
    float inv = 1.f / (pick4(denom, hh) + 1e-16f);
    float sw = pick4(selfw, hh);

#pragma unroll
    for (int j = 0; j < 8; j++) {
        acc[j] += __shfl_xor(acc[j], 16);
        acc[j] += __shfl_xor(acc[j], 32);
    }
    if (q == 0) {
        const float* hp = &h1[(size_t)node * 128 + c * 8];
        const float* bb = &b1[c * 8];
        float o[8];
#pragma unroll
        for (int j = 0; j < 8; j++)
            o[j] = fmaxf((acc[j] + sw * hp[j]) * inv + bb[j], 0.f);
        float4* op = (float4*)&out1[(size_t)node * 128 + c * 8];
        op[0] = make_float4(o[0], o[1], o[2], o[3]);
        op[1] = make_float4(o[4], o[5], o[6], o[7]);
    }
}

// ---------------------------------------------------------------------------
// Layer-2 aggregation (H=1, C=64), same chunked structure: 8 lanes x 16B =
// one 128B row, 8 edges/iter.
// ---------------------------------------------------------------------------
__launch_bounds__(256)
__global__ void aggregate2(const float* __restrict__ h2, const ushort* __restrict__ h16,
                           const float* __restrict__ as2, const float* __restrict__ ad2,
                           const int* __restrict__ rowptr, const int* __restrict__ esrc,
                           const float* __restrict__ b2, float* __restrict__ out, int N) {
    __shared__ float wbuf[4][64];
    __shared__ int   sbuf[4][64];
    int wid = threadIdx.x >> 6, lane = threadIdx.x & 63;
    int node = blockIdx.x * 4 + wid;
    if (node >= N) return;
    float adn = ad2[node];
    float selfw = __expf(leakys(as2[node] + adn));
    int start = rowptr[node], end = rowptr[node + 1];

    int q = lane >> 3, c = lane & 7;    // group q handles edge i+q; ch 8c..8c+7
    float ssum = 0.f;
    float acc[8] = {0.f, 0.f, 0.f, 0.f, 0.f, 0.f, 0.f, 0.f};

    for (int base = start; base < end; base += 64) {
        int cnt = end - base; if (cnt > 64) cnt = 64;
        if (lane < cnt) {
            int s = esrc[base + lane];
            float w = __expf(leakys(as2[s] + adn));
            sbuf[wid][lane] = s;
            wbuf[wid][lane] = w;
            ssum += w;
        }
#pragma unroll 2
        for (int i = 0; i < cnt; i += 8) {
            int ii = i + q;
            int s = 0; float w = 0.f;
            if (ii < cnt) { s = sbuf[wid][ii]; w = wbuf[wid][ii]; }
            half8 hv = *(const half8*)&h16[(size_t)s * 64 + c * 8];
#pragma unroll
            for (int j = 0; j < 8; j++) acc[j] += w * (float)hv[j];
        }
    }
#pragma unroll
    for (int o = 1; o < 64; o <<= 1) ssum += __shfl_xor(ssum, o);
    float inv = 1.f / (ssum + selfw + 1e-16f);

#pragma unroll
    for (int j = 0; j < 8; j++) {
        acc[j] += __shfl_xor(acc[j], 8);
        acc[j] += __shfl_xor(acc[j], 16);
        acc[j] += __shfl_xor(acc[j], 32);
    }
    if (lane < 8) {
        const float* hp = &h2[(size_t)node * 64 + c * 8];
        const float* bb = &b2[c * 8];
        float o[8];
#pragma unroll
        for (int j = 0; j < 8; j++)
            o[j] = (acc[j] + selfw * hp[j]) * inv + bb[j];
        float4* op = (float4*)&out[(size_t)node * 64 + c * 8];
        op[0] = make_float4(o[0], o[1], o[2], o[3]);
        op[1] = make_float4(o[4], o[5], o[6], o[7]);
    }
}

// ---------------------------------------------------------------------------
extern "C" void kernel_launch(void* const* d_in, const int* in_sizes, int n_in,
                              void* d_out, int out_size, void* d_ws, size_t ws_size,
                              hipStream_t stream) {
    const float* x      = (const float*)d_in[0];
    const int*   ei     = (const int*)d_in[1];
    const float* W1     = (const float*)d_in[2];
    const float* att_s1 = (const float*)d_in[3];
    const float* att_d1 = (const float*)d_in[4];
    const float* b1     = (const float*)d_in[5];
    const float* W2     = (const float*)d_in[6];
    const float* att_s2 = (const float*)d_in[7];
    const float* att_d2 = (const float*)d_in[8];
    const float* b2     = (const float*)d_in[9];

    const int N = in_sizes[0] / 128;
    const int E = in_sizes[1] / 2;
    const int NB = (N + 511) >> 9;         // buckets of 512 dst nodes (<=256)

    char* ws = (char*)d_ws;
    size_t off = 0;
    auto alloc = [&](size_t bytes) -> void* {
        off = (off + 255) & ~(size_t)255;
        void* p = ws + off;
        off += bytes;
        return p;
    };
    float* h1     = (float*)alloc((size_t)N * 128 * 4);
    float* out1   = (float*)alloc((size_t)N * 128 * 4);
    ushort* h16   = (ushort*)alloc((size_t)N * 128 * 2);
    float* as1    = (float*)alloc((size_t)N * 4 * 4);
    float* ad1    = (float*)alloc((size_t)N * 4 * 4);
    int*   rowptr = (int*)alloc((size_t)(N + 1) * 4);
    int*   esrc   = (int*)alloc((size_t)E * 4);
    int*   bcounts = (int*)alloc(256 * 4);
    int*   bbase   = (int*)alloc(256 * 4);
    int*   bcursor = (int*)alloc(256 * 4);
    ushort* Wt1h  = (ushort*)alloc(128 * 128 * 2);
    ushort* Wt1l  = (ushort*)alloc(128 * 128 * 2);
    ushort* Wt2h  = (ushort*)alloc(64 * 128 * 2);
    ushort* Wt2l  = (ushort*)alloc(64 * 128 * 2);
    float* h2   = h1;                                  // h1 dead after aggregate1
    float* as2  = (float*)((char*)h1 + (size_t)N * 64 * 4);
    float* ad2  = as2 + N;
    ushort* h16b = h16;
    uint2* ebuf = (uint2*)out1;   // E*8 <= N*512 bytes; dead before aggregate1 writes out1

    const int* srcIdx = ei;
    const int* dstIdx = ei + E;

    hipMemsetAsync(bcounts, 0, 256 * 4, stream);

    prep_w<<<64, 256, 0, stream>>>(W1, Wt1h, Wt1l, 128);
    prep_w<<<32, 256, 0, stream>>>(W2, Wt2h, Wt2l, 64);

    gemm_mfma<128><<<(N + 63) / 64, 256, 0, stream>>>(x, Wt1h, Wt1l, h1, h16,
                                                      att_s1, att_d1, as1, ad1, N);

    bcount<<<1024, 256, 0, stream>>>(dstIdx, bcounts, E);
    bscan<<<1, 256, 0, stream>>>(bcounts, bbase, bcursor, NB);
    bscatter<<<(E + 4095) / 4096, 256, 0, stream>>>(srcIdx, dstIdx, bcursor, ebuf, E);
    bfill<<<NB, 256, 0, stream>>>(ebuf, bbase, rowptr, esrc, N, NB, E);

    aggregate1<<<(N + 3) / 4, 256, 0, stream>>>(h1, h16, as1, ad1, rowptr, esrc,
                                                b1, out1, N);

    gemm_mfma<64><<<(N + 63) / 64, 256, 0, stream>>>(out1, Wt2h, Wt2l, h2, h16b,
                                                     nullptr, nullptr, nullptr, nullptr, N);
    attdot2<<<(N + 3) / 4, 256, 0, stream>>>(h2, att_s2, att_d2, as2, ad2, N);

    aggregate2<<<(N + 3) / 4, 256, 0, stream>>>(h2, h16b, as2, ad2, rowptr, esrc,
                                                b2, (float*)d_out, N);
}

// Round 7
// 269.447 us; speedup vs baseline: 3.8029x; 1.0601x over previous
//
#include <hip/hip_runtime.h>
#include <hip/hip_bf16.h>

#define DEV static __device__ __forceinline__

typedef __attribute__((ext_vector_type(4))) float f32x4;
typedef __attribute__((ext_vector_type(8))) short bf16x8;
typedef __attribute__((ext_vector_type(8))) _Float16 half8;
typedef __attribute__((ext_vector_type(8))) unsigned short u16x8;

DEV float leakys(float v) { return v > 0.f ? v : 0.2f * v; }
DEV float4 add4(float4 a, float4 b) { return make_float4(a.x+b.x, a.y+b.y, a.z+b.z, a.w+b.w); }
DEV float4 leaky4(float4 v) { return make_float4(leakys(v.x), leakys(v.y), leakys(v.z), leakys(v.w)); }
DEV float4 exp4(float4 v) { return make_float4(__expf(v.x), __expf(v.y), __expf(v.z), __expf(v.w)); }
DEV float pick4(float4 v, int i) {
    float r = v.x;
    r = (i == 1) ? v.y : r;
    r = (i == 2) ? v.z : r;
    r = (i == 3) ? v.w : r;
    return r;
}

DEV ushort f2bf(float f) {
    union { float f; unsigned u; } v; v.f = f;
    unsigned u = v.u;
    unsigned r = (u + 0x7FFFu + ((u >> 16) & 1u)) >> 16;   // RNE
    return (ushort)r;
}
DEV float bf2f(ushort h) {
    union { unsigned u; float f; } v; v.u = ((unsigned)h) << 16;
    return v.f;
}
DEV ushort f2h(float f) {
    union { _Float16 h; ushort u; } v;
    v.h = (_Float16)f;
    return v.u;
}

// ---------------------------------------------------------------------------
// One-time W prep: W[K=128][NC] f32 -> transposed bf16 hi/lo  Wt[n][k].
// ---------------------------------------------------------------------------
__global__ void prep_w(const float* __restrict__ W, ushort* __restrict__ Wth,
                       ushort* __restrict__ Wtl, int NC) {
    int i = blockIdx.x * 256 + threadIdx.x;
    if (i >= 128 * NC) return;
    int k = i / NC, n = i % NC;
    float v = W[i];
    ushort hi = f2bf(v);
    ushort lo = f2bf(v - bf2f(hi));
    Wth[n * 128 + k] = hi;
    Wtl[n * 128 + k] = lo;
}

// ---------------------------------------------------------------------------
// MFMA GEMM: C[N][NCOLS] = A[N][128] @ W[128][NCOLS], split-bf16 (3 MFMA).
// A is f32 (AH=false) or fp16 (AH=true). Output: fp16 C16 only.
// Fused attention dots:
//   NCOLS==128 (H=4): wave wv owns cols [32wv,32wv+32) == head wv -> in-wave.
//   NCOLS==64  (H=1): per-wave 16-col partials combined across waves via LDS.
// ---------------------------------------------------------------------------
template <int NCOLS, bool AH>
__launch_bounds__(256, 2)
__global__ void gemm_mfma(const float* __restrict__ A, const ushort* __restrict__ A16,
                          const ushort* __restrict__ Wth, const ushort* __restrict__ Wtl,
                          ushort* __restrict__ C16,
                          const float* __restrict__ att_s, const float* __restrict__ att_d,
                          float* __restrict__ as_out, float* __restrict__ ad_out, int N) {
    constexpr int NT = NCOLS / 64;          // 16-wide n-tiles per wave
    __shared__ ushort Xhi[64 * 128];
    __shared__ ushort Xlo[64 * 128];
    __shared__ float pbs[64][4];
    __shared__ float pbd[64][4];
    const int t = threadIdx.x;
    const int wv = t >> 6, l = t & 63;
    const int l15 = l & 15, lhi = l >> 4;
    const int row0 = blockIdx.x * 64;
    const int n0 = wv * 16 * NT;

    if constexpr (!AH) {
        for (int i = t; i < 2048; i += 256) {
            int r = i >> 5, c4 = i & 31;
            int gr = row0 + r;
            float4 v = make_float4(0.f, 0.f, 0.f, 0.f);
            if (gr < N) v = ((const float4*)A)[(size_t)gr * 32 + c4];
            ushort4 hi, lo;
            hi.x = f2bf(v.x); lo.x = f2bf(v.x - bf2f(hi.x));
            hi.y = f2bf(v.y); lo.y = f2bf(v.y - bf2f(hi.y));
            hi.z = f2bf(v.z); lo.z = f2bf(v.z - bf2f(hi.z));
            hi.w = f2bf(v.w); lo.w = f2bf(v.w - bf2f(hi.w));
            int idx = (r * 128 + c4 * 4) ^ ((r & 7) << 3);
            *(ushort4*)&Xhi[idx] = hi;
            *(ushort4*)&Xlo[idx] = lo;
        }
    } else {
        for (int i = t; i < 1024; i += 256) {
            int r = i >> 4, c8 = i & 15;
            int gr = row0 + r;
            half8 v = (half8){0, 0, 0, 0, 0, 0, 0, 0};
            if (gr < N) v = *(const half8*)&A16[(size_t)gr * 128 + c8 * 8];
            u16x8 hi, lo;
#pragma unroll
            for (int j = 0; j < 8; j++) {
                float f = (float)v[j];
                ushort hb = f2bf(f);
                hi[j] = hb;
                lo[j] = f2bf(f - bf2f(hb));
            }
            int idx = (r * 128 + c8 * 8) ^ ((r & 7) << 3);
            *(u16x8*)&Xhi[idx] = hi;
            *(u16x8*)&Xlo[idx] = lo;
        }
    }
    __syncthreads();

    f32x4 acc[4][NT];
#pragma unroll
    for (int mt = 0; mt < 4; mt++)
#pragma unroll
        for (int nt = 0; nt < NT; nt++) acc[mt][nt] = (f32x4){0.f, 0.f, 0.f, 0.f};

#pragma unroll
    for (int ks = 0; ks < 4; ks++) {
        bf16x8 ah[4], al[4];
#pragma unroll
        for (int mt = 0; mt < 4; mt++) {
            int row = mt * 16 + l15;
            int idx = (row * 128 + ks * 32 + lhi * 8) ^ ((row & 7) << 3);
            ah[mt] = *(const bf16x8*)&Xhi[idx];
            al[mt] = *(const bf16x8*)&Xlo[idx];
        }
#pragma unroll
        for (int nt = 0; nt < NT; nt++) {
            size_t wo = (size_t)(n0 + nt * 16 + l15) * 128 + ks * 32 + lhi * 8;
            bf16x8 bh = *(const bf16x8*)&Wth[wo];
            bf16x8 bl = *(const bf16x8*)&Wtl[wo];
#pragma unroll
            for (int mt = 0; mt < 4; mt++) {
                acc[mt][nt] = __builtin_amdgcn_mfma_f32_16x16x32_bf16(ah[mt], bh, acc[mt][nt], 0, 0, 0);
                acc[mt][nt] = __builtin_amdgcn_mfma_f32_16x16x32_bf16(ah[mt], bl, acc[mt][nt], 0, 0, 0);
                acc[mt][nt] = __builtin_amdgcn_mfma_f32_16x16x32_bf16(al[mt], bh, acc[mt][nt], 0, 0, 0);
            }
        }
    }
#pragma unroll
    for (int mt = 0; mt < 4; mt++) {
#pragma unroll
        for (int j = 0; j < 4; j++) {
            int gr = row0 + mt * 16 + lhi * 4 + j;
            if (gr < N) {
#pragma unroll
                for (int nt = 0; nt < NT; nt++)
                    C16[(size_t)gr * NCOLS + n0 + nt * 16 + l15] = f2h(acc[mt][nt][j]);
            }
        }
    }
    if constexpr (NT == 2) {
        // fused attdot, H=4: head wv = cols [n0, n0+32)
        float as0 = att_s[n0 + l15],       ad0 = att_d[n0 + l15];
        float as1v = att_s[n0 + 16 + l15], ad1v = att_d[n0 + 16 + l15];
#pragma unroll
        for (int mt = 0; mt < 4; mt++) {
#pragma unroll
            for (int j = 0; j < 4; j++) {
                float ps = acc[mt][0][j] * as0 + acc[mt][1][j] * as1v;
                float pd = acc[mt][0][j] * ad0 + acc[mt][1][j] * ad1v;
#pragma unroll
                for (int o = 1; o < 16; o <<= 1) {
                    ps += __shfl_xor(ps, o);
                    pd += __shfl_xor(pd, o);
                }
                if (l15 == 0) {
                    int gr = row0 + mt * 16 + lhi * 4 + j;
                    if (gr < N) {
                        as_out[gr * 4 + wv] = ps;
                        ad_out[gr * 4 + wv] = pd;
                    }
                }
            }
        }
    } else {
        // fused attdot, H=1: wave partials over 16 cols -> LDS -> combine
        float as0 = att_s[n0 + l15], ad0 = att_d[n0 + l15];
#pragma unroll
        for (int mt = 0; mt < 4; mt++) {
#pragma unroll
            for (int j = 0; j < 4; j++) {
                float ps = acc[mt][0][j] * as0;
                float pd = acc[mt][0][j] * ad0;
#pragma unroll
                for (int o = 1; o < 16; o <<= 1) {
                    ps += __shfl_xor(ps, o);
                    pd += __shfl_xor(pd, o);
                }
                if (l15 == 0) {
                    int rl = mt * 16 + lhi * 4 + j;
                    pbs[rl][wv] = ps;
                    pbd[rl][wv] = pd;
                }
            }
        }
        __syncthreads();
        if (t < 64) {
            int gr = row0 + t;
            if (gr < N) {
                as_out[gr] = pbs[t][0] + pbs[t][1] + pbs[t][2] + pbs[t][3];
                ad_out[gr] = pbd[t][0] + pbd[t][1] + pbd[t][2] + pbd[t][3];
            }
        }
    }
}

// ---------------------------------------------------------------------------
// CSR build, bucket counting sort. Bucket = 512 consecutive dst nodes
// (NB = ceil(N/512) <= 256). All scatters land in L2-resident windows.
// ---------------------------------------------------------------------------
__global__ void bcount(const int* __restrict__ dstIdx, int* __restrict__ bcounts, int E) {
    __shared__ int hist[256];
    int t = threadIdx.x;
    hist[t] = 0;
    __syncthreads();
    for (int e = blockIdx.x * 256 + t; e < E; e += gridDim.x * 256)
        atomicAdd(&hist[dstIdx[e] >> 9], 1);
    __syncthreads();
    int h = hist[t];
    if (h) atomicAdd(&bcounts[t], h);
}

__global__ void bscan(const int* __restrict__ bcounts, int* __restrict__ bbase,
                      int* __restrict__ bcursor, int NB) {
    __shared__ int lds[256];
    int t = threadIdx.x;
    int v = (t < NB) ? bcounts[t] : 0;
    lds[t] = v;
    __syncthreads();
    int val = v;
    for (int o = 1; o < 256; o <<= 1) {
        int other = (t >= o) ? lds[t - o] : 0;
        __syncthreads();
        val += other; lds[t] = val;
        __syncthreads();
    }
    if (t < NB) { bbase[t] = val - v; bcursor[t] = val - v; }
}

// per-block multisplit: one ranged atomic per (block,bucket), short coalesced runs
__global__ void bscatter(const int* __restrict__ srcIdx, const int* __restrict__ dstIdx,
                         int* __restrict__ bcursor, uint2* __restrict__ ebuf, int E) {
    __shared__ int hist[256];
    __shared__ int gofs[256];
    int t = threadIdx.x;
    hist[t] = 0;
    __syncthreads();
    int e0 = blockIdx.x * 4096;
    int e1 = min(E, e0 + 4096);
    for (int e = e0 + t; e < e1; e += 256)
        atomicAdd(&hist[dstIdx[e] >> 9], 1);
    __syncthreads();
    int h = hist[t];
    if (h) gofs[t] = atomicAdd(&bcursor[t], h);
    __syncthreads();
    hist[t] = 0;
    __syncthreads();
    for (int e = e0 + t; e < e1; e += 256) {
        int d = dstIdx[e];
        int b = d >> 9;
        int r = atomicAdd(&hist[b], 1);
        uint2 v; v.x = (unsigned)srcIdx[e]; v.y = (unsigned)d;
        ebuf[gofs[b] + r] = v;
    }
}

// one block per bucket: LDS node-histogram -> LDS scan -> rowptr + local fill
__global__ void bfill(const uint2* __restrict__ ebuf, const int* __restrict__ bbase,
                      int* __restrict__ rowptr, int* __restrict__ esrc,
                      int N, int NB, int E) {
    __shared__ int cnt[512];
    __shared__ int lds[256];
    int b = blockIdx.x, t = threadIdx.x;
    int n0 = b << 9;
    cnt[t] = 0; cnt[t + 256] = 0;
    __syncthreads();
    int e0 = bbase[b];
    int e1 = (b + 1 < NB) ? bbase[b + 1] : E;
    for (int e = e0 + t; e < e1; e += 256)
        atomicAdd(&cnt[ebuf[e].y & 511], 1);
    __syncthreads();
    int c0 = cnt[2 * t], c1 = cnt[2 * t + 1];
    int s = c0 + c1;
    lds[t] = s;
    __syncthreads();
    int val = s;
    for (int o = 1; o < 256; o <<= 1) {
        int other = (t >= o) ? lds[t - o] : 0;
        __syncthreads();
        val += other; lds[t] = val;
        __syncthreads();
    }
    int p = val - s;           // exclusive prefix of this thread's pair
    int nrem = N - n0;
    if (2 * t < nrem)     rowptr[n0 + 2 * t]     = e0 + p;
    if (2 * t + 1 < nrem) rowptr[n0 + 2 * t + 1] = e0 + p + c0;
    cnt[2 * t] = p; cnt[2 * t + 1] = p + c0;   // local cursors
    __syncthreads();
    for (int e = e0 + t; e < e1; e += 256) {
        uint2 ed = ebuf[e];
        int r = atomicAdd(&cnt[ed.y & 511], 1);
        esrc[e0 + r] = (int)ed.x;
    }
    if (b == 0 && t == 0) rowptr[N] = E;
}

// ---------------------------------------------------------------------------
// Layer-1 aggregation, single-pass chunked (all-fp16 rows). Per 64-edge
// chunk: phase 1 computes each edge's weight ONCE lane-parallel -> per-wave
// LDS (+denom in regs); phase 2 fp16 gather-FMA, 16 lanes x 16B = one 256B
// row, 4 edges/iter. Self row from h16; output written as fp16.
// ---------------------------------------------------------------------------
__launch_bounds__(256)
__global__ void aggregate1(const ushort* __restrict__ h16,
                           const float* __restrict__ as1, const float* __restrict__ ad1,
                           const int* __restrict__ rowptr, const int* __restrict__ esrc,
                           const float* __restrict__ b1, ushort* __restrict__ out1h, int N) {
    __shared__ float wbuf[4][256];
    __shared__ int   sbuf[4][64];
    int wid = threadIdx.x >> 6, lane = threadIdx.x & 63;
    int node = blockIdx.x * 4 + wid;
    if (node >= N) return;
    float4 asn = *(const float4*)&as1[node * 4];
    float4 adn = *(const float4*)&ad1[node * 4];
    float4 selfw = exp4(leaky4(add4(asn, adn)));
    int start = rowptr[node], end = rowptr[node + 1];

    int q = lane >> 4, c = lane & 15;   // group q handles edge i+q; ch 8c..8c+7
    int hh = c >> 2;                    // head of this lane's 8 channels
    float4 ssum = make_float4(0.f, 0.f, 0.f, 0.f);
    float acc[8] = {0.f, 0.f, 0.f, 0.f, 0.f, 0.f, 0.f, 0.f};

    for (int base = start; base < end; base += 64) {
        int cnt = end - base; if (cnt > 64) cnt = 64;
        // phase 1: per-edge weights (once), denominator partials in regs
        if (lane < cnt) {
            int s = esrc[base + lane];
            float4 w = exp4(leaky4(add4(*(const float4*)&as1[s * 4], adn)));
            sbuf[wid][lane] = s;
            *(float4*)&wbuf[wid][lane * 4] = w;
            ssum = add4(ssum, w);
        }
        // phase 2: fp16 gather-FMA, 4 edges/iter; w,s broadcast from LDS
#pragma unroll 4
        for (int i = 0; i < cnt; i += 4) {
            int ii = i + q;
            int s = 0; float w = 0.f;
            if (ii < cnt) { s = sbuf[wid][ii]; w = wbuf[wid][ii * 4 + hh]; }
            half8 hv = *(const half8*)&h16[(size_t)s * 128 + c * 8];
#pragma unroll
            for (int j = 0; j < 8; j++) acc[j] += w * (float)hv[j];
        }
    }
#pragma unroll
    for (int o = 1; o < 64; o <<= 1) {
        ssum.x += __shfl_xor(ssum.x, o);
        ssum.y += __shfl_xor(ssum.y, o);
        ssum.z += __shfl_xor(ssum.z, o);
        ssum.w += __shfl_xor(ssum.w, o);
    }
    float4 denom = add4(ssum, selfw);
    float inv = 1.f / (pick4(denom, hh) + 1e-16f);
    float sw = pick4(selfw, hh);

#pragma unroll
    for (int j = 0; j < 8; j++) {
        acc[j] += __shfl_xor(acc[j], 16);
        acc[j] += __shfl_xor(acc[j], 32);
    }
    if (q == 0) {
        half8 hs = *(const half8*)&h16[(size_t)node * 128 + c * 8];
        const float* bb = &b1[c * 8];
        half8 ov;
#pragma unroll
        for (int j = 0; j < 8; j++) {
            float oj = fmaxf((acc[j] + sw * (float)hs[j]) * inv + bb[j], 0.f);
            ov[j] = (_Float16)oj;
        }
        *(half8*)&out1h[(size_t)node * 128 + c * 8] = ov;
    }
}

// ---------------------------------------------------------------------------
// Layer-2 aggregation (H=1, C=64), same chunked structure: 8 lanes x 16B =
// one 128B row, 8 edges/iter. Self row from h16b; f32 output (+bias).
// ---------------------------------------------------------------------------
__launch_bounds__(256)
__global__ void aggregate2(const ushort* __restrict__ h16,
                           const float* __restrict__ as2, const float* __restrict__ ad2,
                           const int* __restrict__ rowptr, const int* __restrict__ esrc,
                           const float* __restrict__ b2, float* __restrict__ out, int N) {
    __shared__ float wbuf[4][64];
    __shared__ int   sbuf[4][64];
    int wid = threadIdx.x >> 6, lane = threadIdx.x & 63;
    int node = blockIdx.x * 4 + wid;
    if (node >= N) return;
    float adn = ad2[node];
    float selfw = __expf(leakys(as2[node] + adn));
    int start = rowptr[node], end = rowptr[node + 1];

    int q = lane >> 3, c = lane & 7;    // group q handles edge i+q; ch 8c..8c+7
    float ssum = 0.f;
    float acc[8] = {0.f, 0.f, 0.f, 0.f, 0.f, 0.f, 0.f, 0.f};

    for (int base = start; base < end; base += 64) {
        int cnt = end - base; if (cnt > 64) cnt = 64;
        if (lane < cnt) {
            int s = esrc[base + lane];
            float w = __expf(leakys(as2[s] + adn));
            sbuf[wid][lane] = s;
            wbuf[wid][lane] = w;
            ssum += w;
        }
#pragma unroll 2
        for (int i = 0; i < cnt; i += 8) {
            int ii = i + q;
            int s = 0; float w = 0.f;
            if (ii < cnt) { s = sbuf[wid][ii]; w = wbuf[wid][ii]; }
            half8 hv = *(const half8*)&h16[(size_t)s * 64 + c * 8];
#pragma unroll
            for (int j = 0; j < 8; j++) acc[j] += w * (float)hv[j];
        }
    }
#pragma unroll
    for (int o = 1; o < 64; o <<= 1) ssum += __shfl_xor(ssum, o);
    float inv = 1.f / (ssum + selfw + 1e-16f);

#pragma unroll
    for (int j = 0; j < 8; j++) {
        acc[j] += __shfl_xor(acc[j], 8);
        acc[j] += __shfl_xor(acc[j], 16);
        acc[j] += __shfl_xor(acc[j], 32);
    }
    if (lane < 8) {
        half8 hs = *(const half8*)&h16[(size_t)node * 64 + c * 8];
        const float* bb = &b2[c * 8];
        float o[8];
#pragma unroll
        for (int j = 0; j < 8; j++)
            o[j] = (acc[j] + selfw * (float)hs[j]) * inv + bb[j];
        float4* op = (float4*)&out[(size_t)node * 64 + c * 8];
        op[0] = make_float4(o[0], o[1], o[2], o[3]);
        op[1] = make_float4(o[4], o[5], o[6], o[7]);
    }
}

// ---------------------------------------------------------------------------
extern "C" void kernel_launch(void* const* d_in, const int* in_sizes, int n_in,
                              void* d_out, int out_size, void* d_ws, size_t ws_size,
                              hipStream_t stream) {
    const float* x      = (const float*)d_in[0];
    const int*   ei     = (const int*)d_in[1];
    const float* W1     = (const float*)d_in[2];
    const float* att_s1 = (const float*)d_in[3];
    const float* att_d1 = (const float*)d_in[4];
    const float* b1     = (const float*)d_in[5];
    const float* W2     = (const float*)d_in[6];
    const float* att_s2 = (const float*)d_in[7];
    const float* att_d2 = (const float*)d_in[8];
    const float* b2     = (const float*)d_in[9];

    const int N = in_sizes[0] / 128;
    const int E = in_sizes[1] / 2;
    const int NB = (N + 511) >> 9;         // buckets of 512 dst nodes (<=256)

    char* ws = (char*)d_ws;
    size_t off = 0;
    auto alloc = [&](size_t bytes) -> void* {
        off = (off + 255) & ~(size_t)255;
        void* p = ws + off;
        off += bytes;
        return p;
    };
    ushort* h16   = (ushort*)alloc((size_t)N * 128 * 2);   // layer-1 rows (fp16)
    ushort* out1h = (ushort*)alloc((size_t)N * 128 * 2);   // layer-1 output (fp16)
    float* as1    = (float*)alloc((size_t)N * 4 * 4);
    float* ad1    = (float*)alloc((size_t)N * 4 * 4);
    float* as2    = (float*)alloc((size_t)N * 4);
    float* ad2    = (float*)alloc((size_t)N * 4);
    int*   rowptr = (int*)alloc((size_t)(N + 1) * 4);
    int*   esrc   = (int*)alloc((size_t)E * 4);
    int*   bcounts = (int*)alloc(256 * 4);
    int*   bbase   = (int*)alloc(256 * 4);
    int*   bcursor = (int*)alloc(256 * 4);
    ushort* Wt1h  = (ushort*)alloc(128 * 128 * 2);
    ushort* Wt1l  = (ushort*)alloc(128 * 128 * 2);
    ushort* Wt2h  = (ushort*)alloc(64 * 128 * 2);
    ushort* Wt2l  = (ushort*)alloc(64 * 128 * 2);
    ushort* h16b = h16;           // layer-2 rows reuse h16 (dead after aggregate1)
    uint2* ebuf = (uint2*)out1h;  // E*8 <= N*256 B; consumed before out1h written

    const int* srcIdx = ei;
    const int* dstIdx = ei + E;

    hipMemsetAsync(bcounts, 0, 256 * 4, stream);

    prep_w<<<64, 256, 0, stream>>>(W1, Wt1h, Wt1l, 128);
    prep_w<<<32, 256, 0, stream>>>(W2, Wt2h, Wt2l, 64);

    gemm_mfma<128, false><<<(N + 63) / 64, 256, 0, stream>>>(
        x, nullptr, Wt1h, Wt1l, h16, att_s1, att_d1, as1, ad1, N);

    bcount<<<1024, 256, 0, stream>>>(dstIdx, bcounts, E);
    bscan<<<1, 256, 0, stream>>>(bcounts, bbase, bcursor, NB);
    bscatter<<<(E + 4095) / 4096, 256, 0, stream>>>(srcIdx, dstIdx, bcursor, ebuf, E);
    bfill<<<NB, 256, 0, stream>>>(ebuf, bbase, rowptr, esrc, N, NB, E);

    aggregate1<<<(N + 3) / 4, 256, 0, stream>>>(h16, as1, ad1, rowptr, esrc,
                                                b1, out1h, N);

    gemm_mfma<64, true><<<(N + 63) / 64, 256, 0, stream>>>(
        nullptr, out1h, Wt2h, Wt2l, h16b, att_s2, att_d2, as2, ad2, N);

    aggregate2<<<(N + 3) / 4, 256, 0, stream>>>(h16b, as2, ad2, rowptr, esrc,
                                                b2, (float*)d_out, N);
}